// Round 4
// baseline (174.451 us; speedup 1.0000x reference)
//
#include <hip/hip_runtime.h>
#include <math.h>

#define B_SIZE 8192
#define D_SIZE 256
#define N_CLS 1024
#define CLS_CAP 64
#define PCAP 256
#define ALPHA 2.0f
#define BETA 50.0f
#define BASE 0.5f
#define MARGIN 0.1f

// neg GEMM: 128x128 tile, 4 waves (2x2 of 64x64), NO LDS AT ALL.
// C = E.E^T is an NT GEMM: both MFMA operands are K-contiguous in global
// memory, so each lane global_load_dwordx4's its fragment directly
// (embb[(row)*256 + it*32 + quad*8]). No staging, no barriers, no
// __syncthreads -- waves free-run; register ping-pong gives depth-1
// prefetch; compiler manages vmcnt. XCD swizzle keeps the 4 MB embb
// panel hot in each XCD's private L2.
#define TM 128
#define TK 32
#define NT (B_SIZE / TM)            // 64 tiles per dim
#define NBLK (NT * (NT + 1) / 2)    // 2080 triangular tiles
#define NCONV (B_SIZE * D_SIZE / 1024)   // 2048 convert blocks

typedef __attribute__((ext_vector_type(8))) __bf16 bf16x8;
typedef __attribute__((ext_vector_type(4))) float f32x4;

__device__ __forceinline__ unsigned int enc_f32(float f) {
    unsigned int u = __float_as_uint(f);
    return (u & 0x80000000u) ? ~u : (u | 0x80000000u);
}
__device__ __forceinline__ float dec_f32(unsigned int e) {
    unsigned int u = (e & 0x80000000u) ? (e ^ 0x80000000u) : ~e;
    return __uint_as_float(u);
}

__device__ __forceinline__ unsigned short f2bf(float x) {
    unsigned int u = __float_as_uint(x);
    u += 0x7FFFu + ((u >> 16) & 1u);   // RNE
    return (unsigned short)(u >> 16);
}

// DPP lane-XOR move within 16 lanes (VALU, off the LDS pipe, low latency).
// quad_perm XOR1=0xB1, XOR2=0x4E, row_half_mirror(XOR-7 == XOR-4 once 4-groups
// uniform)=0x141, row_mirror(XOR-15 == XOR-8 once 8-groups uniform)=0x140.
// Values are bit-identical to the __shfl_xor butterfly.
template <int C>
__device__ __forceinline__ float dppx(float x) {
    return __builtin_bit_cast(float, __builtin_amdgcn_update_dpp(
        0, __builtin_bit_cast(int, x), C, 0xF, 0xF, true));
}
__device__ __forceinline__ void red16(float& s, float& m) {
    s += dppx<0xB1>(s);  m = fmaxf(m, dppx<0xB1>(m));
    s += dppx<0x4E>(s);  m = fmaxf(m, dppx<0x4E>(m));
    s += dppx<0x141>(s); m = fmaxf(m, dppx<0x141>(m));
    s += dppx<0x140>(s); m = fmaxf(m, dppx<0x140>(m));
}

// decode unordered pair index p -> (a, b), 0 <= b < a
__device__ __forceinline__ void pair_decode(int p, int& a, int& b) {
    a = (int)((1.0f + sqrtf(1.0f + 8.0f * (float)p)) * 0.5f);
    while (a * (a - 1) / 2 > p) --a;
    while ((a + 1) * a / 2 <= p) ++a;
    b = p - a * (a - 1) / 2;
}

// ---- K1: fused class-blocks (0..N_CLS) + convert blocks (N_CLS..) ----
__global__ __launch_bounds__(256) void conv_pos_kernel(
    const float* __restrict__ emb, const int* __restrict__ labels,
    unsigned short* __restrict__ embb,
    float* __restrict__ pos_min, float* __restrict__ psims,
    int* __restrict__ cls_cnt, int* __restrict__ cls_rows) {
    int t = threadIdx.x;
    if (blockIdx.x >= N_CLS) {
        int i = ((blockIdx.x - N_CLS) * 256 + t) * 4;
        float4 v = *(const float4*)(&emb[i]);
        ushort4 o;
        o.x = f2bf(v.x); o.y = f2bf(v.y); o.z = f2bf(v.z); o.w = f2bf(v.w);
        *(ushort4*)(&embb[i]) = o;
        return;
    }
    int cls = blockIdx.x;
    __shared__ int rs[CLS_CAP];
    __shared__ unsigned int smin[CLS_CAP];
    __shared__ int lcnt;
    if (t == 0) lcnt = 0;
    if (t < CLS_CAP) smin[t] = 0xFF800000u;  // enc(+inf)
    __syncthreads();
    const int4* lab4 = (const int4*)labels;
    for (int i = t; i < B_SIZE / 4; i += 256) {
        int4 L = lab4[i];
        if (L.x == cls) { int p = atomicAdd(&lcnt, 1); if (p < CLS_CAP) rs[p] = 4 * i; }
        if (L.y == cls) { int p = atomicAdd(&lcnt, 1); if (p < CLS_CAP) rs[p] = 4 * i + 1; }
        if (L.z == cls) { int p = atomicAdd(&lcnt, 1); if (p < CLS_CAP) rs[p] = 4 * i + 2; }
        if (L.w == cls) { int p = atomicAdd(&lcnt, 1); if (p < CLS_CAP) rs[p] = 4 * i + 3; }
    }
    __syncthreads();
    int c = min(lcnt, CLS_CAP);
    if (t == 0) cls_cnt[cls] = c;
    if (t < c) cls_rows[cls * CLS_CAP + t] = rs[t];
    int np = c * (c - 1) / 2;
    for (int base = 0; base < np * 8; base += 256) {
        int slot = base + t;
        if (slot < np * 8) {
            int p = slot >> 3, l = slot & 7;   // 8 aligned lanes per pair
            int a, b; pair_decode(p, a, b);
            const float4* pa = (const float4*)(emb + (size_t)rs[a] * D_SIZE) + l * 8;
            const float4* pb = (const float4*)(emb + (size_t)rs[b] * D_SIZE) + l * 8;
            float s = 0.0f;
#pragma unroll
            for (int k = 0; k < 8; ++k) {
                float4 x = pa[k], y = pb[k];
                s = fmaf(x.x, y.x, fmaf(x.y, y.y, fmaf(x.z, y.z, fmaf(x.w, y.w, s))));
            }
            s += __shfl_xor(s, 1, 64);
            s += __shfl_xor(s, 2, 64);
            s += __shfl_xor(s, 4, 64);
            if (l == 0) {
                if (p < PCAP) psims[cls * PCAP + p] = s;
                unsigned int e = enc_f32(s);
                atomicMin(&smin[a], e);
                atomicMin(&smin[b], e);
            }
        }
    }
    __syncthreads();
    if (t < c) pos_min[rs[t]] = dec_f32(smin[t]);
}

// ---- K2: the ONE GEMM (triangular tiles), register-direct, barrier-free ----
// part[k*B + row]: m-side writes k=bj (bj>=bi), n-side k=bi (bi<bj).
// C/D layout (16x16x32): col = lane&15, row = (lane>>4)*4 + reg  [m89/m91]
// A-fragment (f, it) for lane (col,quad) = 16 contiguous bytes at
//   embb[(m0 + wm*64 + f*16 + col)*256 + it*32 + quad*8]   (B same with n0,wn)
// -- identical to what the old stage-swizzle + read-swizzle path delivered
// (the two XORs cancel), so MFMA semantics are unchanged.
__global__ __launch_bounds__(256, 3) void neg_kernel(
    const unsigned short* __restrict__ embb, const int* __restrict__ labels,
    const float* __restrict__ pos_min,
    float* __restrict__ part_sum, float* __restrict__ part_max)
{
    // XCD-aware swizzle: 2080 % 8 == 0 -> bijective chunk map; keeps each
    // XCD's 260-tile range re-reading the same embb panels from its L2.
    int bt = (blockIdx.x & 7) * (NBLK >> 3) + (blockIdx.x >> 3);
    int bi = 0, rem = bt;
    while (rem >= (NT - bi)) { rem -= (NT - bi); ++bi; }
    const int bj = bi + rem;
    const int m0 = bi * TM, n0 = bj * TM;
    const bool isdiag = (bi == bj);

    const int tid = threadIdx.x;
    const int lane = tid & 63;
    const int w = tid >> 6;
    const int wm = w >> 1, wn = w & 1;
    const int col = lane & 15;
    const int quad = lane >> 4;

    const unsigned short* pA = embb + (size_t)(m0 + wm * 64 + col) * D_SIZE + quad * 8;
    const unsigned short* pB = embb + (size_t)(n0 + wn * 64 + col) * D_SIZE + quad * 8;

    f32x4 acc[4][4];
#pragma unroll
    for (int fi = 0; fi < 4; ++fi)
#pragma unroll
        for (int fj = 0; fj < 4; ++fj)
            acc[fi][fj] = (f32x4){0.0f, 0.0f, 0.0f, 0.0f};

    // register ping-pong (P/Q), fully static (rule-20: no runtime indexing)
    bf16x8 aP[4], bP[4], aQ[4], bQ[4];
#define LDF(DA, DB, IT)                                                       \
    {                                                                         \
        _Pragma("unroll")                                                     \
        for (int f = 0; f < 4; ++f) {                                         \
            DA[f] = __builtin_bit_cast(bf16x8,                                \
                *(const uint4*)(pA + (size_t)f * 16 * D_SIZE + (IT) * TK));   \
            DB[f] = __builtin_bit_cast(bf16x8,                                \
                *(const uint4*)(pB + (size_t)f * 16 * D_SIZE + (IT) * TK));   \
        }                                                                     \
    }
#define MMF(SA, SB)                                                           \
    {                                                                         \
        _Pragma("unroll")                                                     \
        for (int fi = 0; fi < 4; ++fi)                                        \
            _Pragma("unroll")                                                 \
            for (int fj = 0; fj < 4; ++fj)                                    \
                acc[fi][fj] = __builtin_amdgcn_mfma_f32_16x16x32_bf16(        \
                    SA[fi], SB[fj], acc[fi][fj], 0, 0, 0);                    \
    }

    LDF(aP, bP, 0)
    LDF(aQ, bQ, 1)
    MMF(aP, bP)        // it=0 (loads for it=2 issue below, hide under MFMA)
    LDF(aP, bP, 2)
    MMF(aQ, bQ)        // it=1
    LDF(aQ, bQ, 3)
    MMF(aP, bP)        // it=2
    LDF(aP, bP, 4)
    MMF(aQ, bQ)        // it=3
    LDF(aQ, bQ, 5)
    MMF(aP, bP)        // it=4
    LDF(aP, bP, 6)
    MMF(aQ, bQ)        // it=5
    LDF(aQ, bQ, 7)
    MMF(aP, bP)        // it=6
    MMF(aQ, bQ)        // it=7
#undef LDF
#undef MMF

    // ---- epilogue: both sim directions per element, one exp each ----
    int ljv[4]; float pmc[4], nsn[4], nmx[4];
#pragma unroll
    for (int fj = 0; fj < 4; ++fj) {
        int cl = wn * 64 + fj * 16 + col;
        ljv[fj] = labels[n0 + cl];
        pmc[fj] = pos_min[n0 + cl] - MARGIN;
        nsn[fj] = 0.0f;
        nmx[fj] = -__builtin_inff();
    }

#pragma unroll
    for (int fi = 0; fi < 4; ++fi) {
        int rl0 = wm * 64 + fi * 16 + quad * 4;
        int gi0 = m0 + rl0;
        int lir[4]; float pmr[4], msn[4], mmx[4];
#pragma unroll
        for (int r = 0; r < 4; ++r) {
            lir[r] = labels[gi0 + r];
            pmr[r] = pos_min[gi0 + r] - MARGIN;
            msn[r] = 0.0f;
            mmx[r] = -__builtin_inff();
        }
#pragma unroll
        for (int fj = 0; fj < 4; ++fj) {
#pragma unroll
            for (int r = 0; r < 4; ++r) {
                float s = acc[fi][fj][r];
                if (lir[r] != ljv[fj]) {
                    float e = __expf(BETA * (s - BASE));
                    mmx[r] = fmaxf(mmx[r], s);
                    if (s > pmr[r]) msn[r] += e;
                    nmx[fj] = fmaxf(nmx[fj], s);
                    if (s > pmc[fj]) nsn[fj] += e;
                }
            }
        }
        // 16-lane (col) reduction via DPP — VALU, no LDS pipe
#pragma unroll
        for (int r = 0; r < 4; ++r) red16(msn[r], mmx[r]);
        if (col == 0) {
            *(float4*)(&part_sum[(size_t)bj * B_SIZE + gi0]) =
                make_float4(msn[0], msn[1], msn[2], msn[3]);
            *(float4*)(&part_max[(size_t)bj * B_SIZE + gi0]) =
                make_float4(mmx[0], mmx[1], mmx[2], mmx[3]);
        }
    }
    if (!isdiag) {
#pragma unroll
        for (int m = 16; m < 64; m <<= 1) {
#pragma unroll
            for (int fj = 0; fj < 4; ++fj) {
                nsn[fj] += __shfl_xor(nsn[fj], m, 64);
                nmx[fj] = fmaxf(nmx[fj], __shfl_xor(nmx[fj], m, 64));
            }
        }
        if (quad == 0) {
#pragma unroll
            for (int fj = 0; fj < 4; ++fj) {
                int gj = n0 + wn * 64 + fj * 16 + col;
                part_sum[(size_t)bi * B_SIZE + gj] = nsn[fj];
                part_max[(size_t)bi * B_SIZE + gj] = nmx[fj];
            }
        }
    }
}

// ---- K3: per-class reduce partials (8 lanes/row) + sum_pos + per-class term ----
__global__ __launch_bounds__(256) void final_kernel(
    const float* __restrict__ emb, const int* __restrict__ cls_cnt,
    const int* __restrict__ cls_rows, const float* __restrict__ psims,
    const float* __restrict__ part_sum, const float* __restrict__ part_max,
    float* __restrict__ cls_term, float* __restrict__ cls_valid) {
    int cls = blockIdx.x;
    __shared__ int rs[CLS_CAP];
    __shared__ float snm[CLS_CAP];
    __shared__ float sneg[CLS_CAP];
    __shared__ float ssum[CLS_CAP];
    int t = threadIdx.x;
    int c = min(cls_cnt[cls], CLS_CAP);
    if (t < CLS_CAP) ssum[t] = 0.0f;
    if (t < c) rs[t] = cls_rows[cls * CLS_CAP + t];
    __syncthreads();
    // reduce the 64 neg partials per row; 8 lanes per row for load parallelism
    {
        int l = t & 7;
        for (int rr = t >> 3; rr < c; rr += 32) {
            int row = rs[rr];
            float s = 0.0f, m = -__builtin_inff();
#pragma unroll
            for (int k = 0; k < 8; ++k) {
                s += part_sum[(size_t)(l * 8 + k) * B_SIZE + row];
                m = fmaxf(m, part_max[(size_t)(l * 8 + k) * B_SIZE + row]);
            }
            s += __shfl_xor(s, 1, 64); m = fmaxf(m, __shfl_xor(m, 1, 64));
            s += __shfl_xor(s, 2, 64); m = fmaxf(m, __shfl_xor(m, 2, 64));
            s += __shfl_xor(s, 4, 64); m = fmaxf(m, __shfl_xor(m, 4, 64));
            if (l == 0) { sneg[rr] = s; snm[rr] = m; }
        }
    }
    __syncthreads();
    int np = c * (c - 1) / 2;
    if (np <= PCAP) {
        for (int p = t; p < np; p += 256) {
            float s = psims[cls * PCAP + p];
            int a, b; pair_decode(p, a, b);
            float e = __expf(-ALPHA * (s - BASE));
            if (s - MARGIN < snm[a]) atomicAdd(&ssum[a], e);
            if (s - MARGIN < snm[b]) atomicAdd(&ssum[b], e);
        }
    } else {
        // fallback: recompute dots, 8 lanes per pair
        for (int base = 0; base < np * 8; base += 256) {
            int slot = base + t;
            if (slot < np * 8) {
                int p = slot >> 3, l = slot & 7;
                int a, b; pair_decode(p, a, b);
                const float4* pa = (const float4*)(emb + (size_t)rs[a] * D_SIZE) + l * 8;
                const float4* pb = (const float4*)(emb + (size_t)rs[b] * D_SIZE) + l * 8;
                float s = 0.0f;
#pragma unroll
                for (int k = 0; k < 8; ++k) {
                    float4 x = pa[k], y = pb[k];
                    s = fmaf(x.x, y.x, fmaf(x.y, y.y, fmaf(x.z, y.z, fmaf(x.w, y.w, s))));
                }
                s += __shfl_xor(s, 1, 64);
                s += __shfl_xor(s, 2, 64);
                s += __shfl_xor(s, 4, 64);
                if (l == 0) {
                    float e = __expf(-ALPHA * (s - BASE));
                    if (s - MARGIN < snm[a]) atomicAdd(&ssum[a], e);
                    if (s - MARGIN < snm[b]) atomicAdd(&ssum[b], e);
                }
            }
        }
    }
    __syncthreads();
    // per-class term: rows live on threads 0..c-1 (all in wave 0) -> shfl reduce
    if (t < 64) {
        float term = 0.0f, valid = 0.0f;
        if (t < c) {
            float sp = ssum[t], sn = sneg[t];
            if (sp > 0.0f && sn > 0.0f) {
                term = log1pf(sp) * (1.0f / ALPHA) + log1pf(sn) * (1.0f / BETA);
                valid = 1.0f;
            }
        }
#pragma unroll
        for (int m = 1; m < 64; m <<= 1) {
            term += __shfl_xor(term, m, 64);
            valid += __shfl_xor(valid, m, 64);
        }
        if (t == 0) { cls_term[cls] = term; cls_valid[cls] = valid; }
    }
}

// ---- K4: fold 1024 class terms -> out ----
__global__ __launch_bounds__(256) void finalize_kernel(
    const float* __restrict__ cls_term, const float* __restrict__ cls_valid,
    float* __restrict__ out) {
    __shared__ float st[256];
    __shared__ float sc[256];
    int t = threadIdx.x;
    float tot = 0.0f, cnt = 0.0f;
#pragma unroll
    for (int i = 0; i < N_CLS / 256; ++i) {
        tot += cls_term[i * 256 + t];
        cnt += cls_valid[i * 256 + t];
    }
    st[t] = tot; sc[t] = cnt;
    __syncthreads();
    for (int s = 128; s > 0; s >>= 1) {
        if (t < s) { st[t] += st[t + s]; sc[t] += sc[t + s]; }
        __syncthreads();
    }
    if (t == 0) out[0] = st[0] / fmaxf(sc[0], 1.0f);
}

extern "C" void kernel_launch(void* const* d_in, const int* in_sizes, int n_in,
                              void* d_out, int out_size, void* d_ws, size_t ws_size,
                              hipStream_t stream) {
    const float* emb = (const float*)d_in[0];
    const int* labels = (const int*)d_in[1];
    float* out = (float*)d_out;

    // ws: embb 4MB | part_sum 2MB | part_max 2MB | psims 1MB | cls_rows 256KB |
    //     pos_min 32KB | cls_term 4KB | cls_valid 4KB | cls_cnt 4KB
    unsigned short* embb = (unsigned short*)d_ws;
    float* part_sum = (float*)(embb + (size_t)B_SIZE * D_SIZE);
    float* part_max = part_sum + (size_t)NT * B_SIZE;
    float* psims = part_max + (size_t)NT * B_SIZE;
    int* cls_rows = (int*)(psims + (size_t)N_CLS * PCAP);
    float* pos_min = (float*)(cls_rows + N_CLS * CLS_CAP);
    float* cls_term = pos_min + B_SIZE;
    float* cls_valid = cls_term + N_CLS;
    int* cls_cnt = (int*)(cls_valid + N_CLS);

    conv_pos_kernel<<<dim3(N_CLS + NCONV), dim3(256), 0, stream>>>(
        emb, labels, embb, pos_min, psims, cls_cnt, cls_rows);
    neg_kernel<<<dim3(NBLK), dim3(256), 0, stream>>>(
        embb, labels, pos_min, part_sum, part_max);
    final_kernel<<<dim3(N_CLS), dim3(256), 0, stream>>>(
        emb, cls_cnt, cls_rows, psims, part_sum, part_max, cls_term, cls_valid);
    finalize_kernel<<<dim3(1), dim3(256), 0, stream>>>(cls_term, cls_valid, out);
}

// Round 6
// 160.261 us; speedup vs baseline: 1.0885x; 1.0885x over previous
//
#include <hip/hip_runtime.h>
#include <math.h>

#define B_SIZE 8192
#define D_SIZE 256
#define N_CLS 1024
#define CLS_CAP 64
#define PCAP 256
#define ALPHA 2.0f
#define BETA 50.0f
#define BASE 0.5f
#define MARGIN 0.1f

// neg GEMM tiling: 128x128 tile, BK=32 double-buffered LDS (32 KB), 4 waves.
// TWO triangular tiles per block (grid 1040): tile-1's prologue staging is
// issued in tile-0's last K-slot so its load latency hides under tile-0's
// epilogue; per-block fixed costs amortize 2x. Epilogue is branch-free via
// the -3 sentinel (exp2 underflows to 0 for same-class elements).
#define TM 128
#define TK 32
#define NT (B_SIZE / TM)            // 64 tiles per dim
#define NBLK (NT * (NT + 1) / 2)    // 2080 triangular tiles
#define NPAIR (NBLK / 2)            // 1040 blocks, 2 tiles each
#define NCONV (B_SIZE * D_SIZE / 1024)   // 2048 convert blocks

typedef __attribute__((ext_vector_type(8))) __bf16 bf16x8;
typedef __attribute__((ext_vector_type(4))) float f32x4;

__device__ __forceinline__ unsigned int enc_f32(float f) {
    unsigned int u = __float_as_uint(f);
    return (u & 0x80000000u) ? ~u : (u | 0x80000000u);
}
__device__ __forceinline__ float dec_f32(unsigned int e) {
    unsigned int u = (e & 0x80000000u) ? (e ^ 0x80000000u) : ~e;
    return __uint_as_float(u);
}

__device__ __forceinline__ unsigned short f2bf(float x) {
    unsigned int u = __float_as_uint(x);
    u += 0x7FFFu + ((u >> 16) & 1u);   // RNE
    return (unsigned short)(u >> 16);
}

__device__ __forceinline__ void glds16(const unsigned short* g, const unsigned char* l) {
    __builtin_amdgcn_global_load_lds((const __attribute__((address_space(1))) void*)g,
                                     (__attribute__((address_space(3))) void*)l, 16, 0, 0);
}

// fast 2^x: v_exp_f32 directly (HIP has no __exp2f; glibc macro collision)
__device__ __forceinline__ float fexp2(float x) {
    return __builtin_amdgcn_exp2f(x);
}

// DPP lane-XOR within 16 lanes (VALU pipe, low latency); bit-identical to
// the __shfl_xor butterfly (group totals lane-replicated at each step).
template <int C>
__device__ __forceinline__ float dppx(float x) {
    return __builtin_bit_cast(float, __builtin_amdgcn_update_dpp(
        0, __builtin_bit_cast(int, x), C, 0xF, 0xF, true));
}
__device__ __forceinline__ void red16(float& s, float& m) {
    s += dppx<0xB1>(s);  m = fmaxf(m, dppx<0xB1>(m));
    s += dppx<0x4E>(s);  m = fmaxf(m, dppx<0x4E>(m));
    s += dppx<0x141>(s); m = fmaxf(m, dppx<0x141>(m));
    s += dppx<0x140>(s); m = fmaxf(m, dppx<0x140>(m));
}

// decode unordered pair index p -> (a, b), 0 <= b < a
__device__ __forceinline__ void pair_decode(int p, int& a, int& b) {
    a = (int)((1.0f + sqrtf(1.0f + 8.0f * (float)p)) * 0.5f);
    while (a * (a - 1) / 2 > p) --a;
    while ((a + 1) * a / 2 <= p) ++a;
    b = p - a * (a - 1) / 2;
}

// ---- K1: fused class-blocks (0..N_CLS) + convert blocks (N_CLS..) ----
__global__ __launch_bounds__(256) void conv_pos_kernel(
    const float* __restrict__ emb, const int* __restrict__ labels,
    unsigned short* __restrict__ embb,
    float* __restrict__ pos_min, float* __restrict__ psims,
    int* __restrict__ cls_cnt, int* __restrict__ cls_rows) {
    int t = threadIdx.x;
    if (blockIdx.x >= N_CLS) {
        int i = ((blockIdx.x - N_CLS) * 256 + t) * 4;
        float4 v = *(const float4*)(&emb[i]);
        ushort4 o;
        o.x = f2bf(v.x); o.y = f2bf(v.y); o.z = f2bf(v.z); o.w = f2bf(v.w);
        *(ushort4*)(&embb[i]) = o;
        return;
    }
    int cls = blockIdx.x;
    __shared__ int rs[CLS_CAP];
    __shared__ unsigned int smin[CLS_CAP];
    __shared__ int lcnt;
    if (t == 0) lcnt = 0;
    if (t < CLS_CAP) smin[t] = 0xFF800000u;  // enc(+inf)
    __syncthreads();
    const int4* lab4 = (const int4*)labels;
    for (int i = t; i < B_SIZE / 4; i += 256) {
        int4 L = lab4[i];
        if (L.x == cls) { int p = atomicAdd(&lcnt, 1); if (p < CLS_CAP) rs[p] = 4 * i; }
        if (L.y == cls) { int p = atomicAdd(&lcnt, 1); if (p < CLS_CAP) rs[p] = 4 * i + 1; }
        if (L.z == cls) { int p = atomicAdd(&lcnt, 1); if (p < CLS_CAP) rs[p] = 4 * i + 2; }
        if (L.w == cls) { int p = atomicAdd(&lcnt, 1); if (p < CLS_CAP) rs[p] = 4 * i + 3; }
    }
    __syncthreads();
    int c = min(lcnt, CLS_CAP);
    if (t == 0) cls_cnt[cls] = c;
    if (t < c) cls_rows[cls * CLS_CAP + t] = rs[t];
    int np = c * (c - 1) / 2;
    for (int base = 0; base < np * 8; base += 256) {
        int slot = base + t;
        if (slot < np * 8) {
            int p = slot >> 3, l = slot & 7;   // 8 aligned lanes per pair
            int a, b; pair_decode(p, a, b);
            const float4* pa = (const float4*)(emb + (size_t)rs[a] * D_SIZE) + l * 8;
            const float4* pb = (const float4*)(emb + (size_t)rs[b] * D_SIZE) + l * 8;
            float s = 0.0f;
#pragma unroll
            for (int k = 0; k < 8; ++k) {
                float4 x = pa[k], y = pb[k];
                s = fmaf(x.x, y.x, fmaf(x.y, y.y, fmaf(x.z, y.z, fmaf(x.w, y.w, s))));
            }
            s += __shfl_xor(s, 1, 64);
            s += __shfl_xor(s, 2, 64);
            s += __shfl_xor(s, 4, 64);
            if (l == 0) {
                if (p < PCAP) psims[cls * PCAP + p] = s;
                unsigned int e = enc_f32(s);
                atomicMin(&smin[a], e);
                atomicMin(&smin[b], e);
            }
        }
    }
    __syncthreads();
    if (t < c) pos_min[rs[t]] = dec_f32(smin[t]);
}

// ---- K2: the ONE GEMM, 2 triangular tiles per block ----
// part[k*B + row]: m-side writes k=bj (bj>=bi), n-side k=bi (bi<bj).
// C/D layout (16x16x32): col = lane&15, row = (lane>>4)*4 + reg  [m89/m91]
__global__ __launch_bounds__(256, 4) void neg_kernel(
    const unsigned short* __restrict__ embb, const int* __restrict__ labels,
    const float* __restrict__ pos_min,
    float* __restrict__ part_sum, float* __restrict__ part_max)
{
    // XCD-aware swizzle over tile PAIRS: 1040 % 8 == 0 -> bijective chunks
    // of 130; adjacent tiles share row panels -> L2-friendly.
    const int pg = (blockIdx.x & 7) * (NPAIR >> 3) + (blockIdx.x >> 3);
    // decode tile0 (bi,bj), tile1 = next triangular index
    int bi = 0, rem = pg * 2;
    while (rem >= (NT - bi)) { rem -= (NT - bi); ++bi; }
    const int bj = bi + rem;
    int bi1 = bi, bj1 = bj + 1;
    if (bj1 >= NT) { ++bi1; bj1 = bi1; }

    const int tid = threadIdx.x;
    const int lane = tid & 63;
    const int w = tid >> 6;
    const int wm = w >> 1, wn = w & 1;

    __shared__ unsigned char As[2][TM * 64];
    __shared__ unsigned char Bs[2][TM * 64];

    const int sr = (lane >> 2);            // row-within-16 for staging
    // swizzle chunk: (r>>1)&3 with r = w*32 + s*16 + sr; (s*16)&6==0 and
    // (w*32)&6==0 after >>1, so it reduces to (sr>>1)&3 -> s/w-independent.
    const int sc = ((lane & 3) ^ ((sr >> 1) & 3));
    const unsigned short* gA[2];
    const unsigned short* gB[2];
    int lofs[2];
#pragma unroll
    for (int s = 0; s < 2; ++s) {
        int r = w * 32 + s * 16 + sr;
        gA[s] = embb + (size_t)(bi * TM + r) * D_SIZE + sc * 8;
        gB[s] = embb + (size_t)(bj * TM + r) * D_SIZE + sc * 8;
        lofs[s] = (w * 32 + s * 16) * 64;
    }
#pragma unroll
    for (int s = 0; s < 2; ++s) { glds16(gA[s], As[0] + lofs[s]); glds16(gB[s], Bs[0] + lofs[s]); }

    const int col = lane & 15;
    const int quad = lane >> 4;
    const int xsw = (quad ^ ((col >> 1) & 3)) * 16;
    const int aoff0 = (wm * 64 + col) * 64 + xsw;
    const int boff0 = (wn * 64 + col) * 64 + xsw;

    f32x4 acc[4][4];
#pragma unroll
    for (int fi = 0; fi < 4; ++fi)
#pragma unroll
        for (int fj = 0; fj < 4; ++fj)
            acc[fi][fj] = (f32x4){0.0f, 0.0f, 0.0f, 0.0f};

    // K-loop: r2-proven 2-buffer structure. TAIL runs in the it==7 slot
    // (instead of a next-k stage) — used to issue tile-1's prologue.
#define KLOOP(TAIL)                                                           \
    _Pragma("unroll")                                                         \
    for (int it = 0; it < D_SIZE / TK; ++it) {                                \
        const int st = it & 1;                                                \
        __syncthreads();                                                      \
        if (it + 1 < D_SIZE / TK) {                                           \
            const int k1 = (it + 1) * TK;                                     \
            _Pragma("unroll")                                                 \
            for (int s = 0; s < 2; ++s) {                                     \
                glds16(gA[s] + k1, As[st ^ 1] + lofs[s]);                     \
                glds16(gB[s] + k1, Bs[st ^ 1] + lofs[s]);                     \
            }                                                                 \
        } else { TAIL }                                                       \
        bf16x8 af[4], bf[4];                                                  \
        _Pragma("unroll")                                                     \
        for (int f = 0; f < 4; ++f) {                                         \
            af[f] = __builtin_bit_cast(bf16x8, *(const uint4*)(As[st] + aoff0 + f * 1024)); \
            bf[f] = __builtin_bit_cast(bf16x8, *(const uint4*)(Bs[st] + boff0 + f * 1024)); \
        }                                                                     \
        _Pragma("unroll")                                                     \
        for (int fi = 0; fi < 4; ++fi)                                        \
            _Pragma("unroll")                                                 \
            for (int fj = 0; fj < 4; ++fj)                                    \
                acc[fi][fj] = __builtin_amdgcn_mfma_f32_16x16x32_bf16(        \
                    af[fi], bf[fj], acc[fi][fj], 0, 0, 0);                    \
    }

    // Branch-free epilogue: sm = diff-class ? s : -3 (sims are in [-1,1]).
    // exp2(fma(-3,K1,K2)) = 2^-252.5 -> 0, so masked elements contribute 0
    // to sums (doubly guarded by the threshold cndmask) and -3 < any real
    // sim for the maxes.
#define EPILOG(BI, BJ)                                                        \
    {                                                                         \
        const int m0e = (BI) * TM, n0e = (BJ) * TM;                           \
        const float K1 = 72.13475204444817f;   /* BETA*log2(e) */             \
        const float K2 = -36.067376022224085f; /* -BETA*BASE*log2(e) */       \
        int ljv[4]; float pmc[4], nsn[4], nmx[4];                             \
        _Pragma("unroll")                                                     \
        for (int fj = 0; fj < 4; ++fj) {                                      \
            int cl = wn * 64 + fj * 16 + col;                                 \
            ljv[fj] = labels[n0e + cl];                                       \
            pmc[fj] = pos_min[n0e + cl] - MARGIN;                             \
            nsn[fj] = 0.0f;                                                   \
            nmx[fj] = -3.0f;                                                  \
        }                                                                     \
        _Pragma("unroll")                                                     \
        for (int fi = 0; fi < 4; ++fi) {                                      \
            int gi0 = m0e + wm * 64 + fi * 16 + quad * 4;                     \
            int lir[4]; float pmr[4], msn[4], mmx[4];                         \
            _Pragma("unroll")                                                 \
            for (int r = 0; r < 4; ++r) {                                     \
                lir[r] = labels[gi0 + r];                                     \
                pmr[r] = pos_min[gi0 + r] - MARGIN;                           \
                msn[r] = 0.0f;                                                \
                mmx[r] = -3.0f;                                               \
            }                                                                 \
            _Pragma("unroll")                                                 \
            for (int fj = 0; fj < 4; ++fj) {                                  \
                _Pragma("unroll")                                             \
                for (int r = 0; r < 4; ++r) {                                 \
                    float s = acc[fi][fj][r];                                 \
                    float sm = (lir[r] != ljv[fj]) ? s : -3.0f;               \
                    float e = fexp2(fmaf(sm, K1, K2));                        \
                    mmx[r] = fmaxf(mmx[r], sm);                               \
                    nmx[fj] = fmaxf(nmx[fj], sm);                             \
                    msn[r] += (sm > pmr[r]) ? e : 0.0f;                       \
                    nsn[fj] += (sm > pmc[fj]) ? e : 0.0f;                     \
                }                                                             \
            }                                                                 \
            _Pragma("unroll")                                                 \
            for (int r = 0; r < 4; ++r) red16(msn[r], mmx[r]);                \
            if (col == 0) {                                                   \
                *(float4*)(&part_sum[(size_t)(BJ) * B_SIZE + gi0]) =          \
                    make_float4(msn[0], msn[1], msn[2], msn[3]);              \
                *(float4*)(&part_max[(size_t)(BJ) * B_SIZE + gi0]) =          \
                    make_float4(mmx[0], mmx[1], mmx[2], mmx[3]);              \
            }                                                                 \
        }                                                                     \
        if ((BI) != (BJ)) {                                                   \
            _Pragma("unroll")                                                 \
            for (int m = 16; m < 64; m <<= 1) {                               \
                _Pragma("unroll")                                             \
                for (int fj = 0; fj < 4; ++fj) {                              \
                    nsn[fj] += __shfl_xor(nsn[fj], m, 64);                    \
                    nmx[fj] = fmaxf(nmx[fj], __shfl_xor(nmx[fj], m, 64));     \
                }                                                             \
            }                                                                 \
            if (quad == 0) {                                                  \
                _Pragma("unroll")                                             \
                for (int fj = 0; fj < 4; ++fj) {                              \
                    int gj = n0e + wn * 64 + fj * 16 + col;                   \
                    part_sum[(size_t)(BI) * B_SIZE + gj] = nsn[fj];           \
                    part_max[(size_t)(BI) * B_SIZE + gj] = nmx[fj];           \
                }                                                             \
            }                                                                 \
        }                                                                     \
    }

    // ---- tile 0: K-loop; tail issues tile-1's prologue into buf 0 ----
    KLOOP({
        _Pragma("unroll")
        for (int s = 0; s < 2; ++s) {
            int r = w * 32 + s * 16 + sr;
            gA[s] = embb + (size_t)(bi1 * TM + r) * D_SIZE + sc * 8;
            gB[s] = embb + (size_t)(bj1 * TM + r) * D_SIZE + sc * 8;
            glds16(gA[s], As[0] + lofs[s]);
            glds16(gB[s], Bs[0] + lofs[s]);
        }
    })
    EPILOG(bi, bj)

#pragma unroll
    for (int fi = 0; fi < 4; ++fi)
#pragma unroll
        for (int fj = 0; fj < 4; ++fj)
            acc[fi][fj] = (f32x4){0.0f, 0.0f, 0.0f, 0.0f};

    // ---- tile 1 ----
    KLOOP({})
    EPILOG(bi1, bj1)
#undef KLOOP
#undef EPILOG
}

// ---- K3: per-class reduce partials (8 lanes/row) + sum_pos + per-class term ----
__global__ __launch_bounds__(256) void final_kernel(
    const float* __restrict__ emb, const int* __restrict__ cls_cnt,
    const int* __restrict__ cls_rows, const float* __restrict__ psims,
    const float* __restrict__ part_sum, const float* __restrict__ part_max,
    float* __restrict__ cls_term, float* __restrict__ cls_valid) {
    int cls = blockIdx.x;
    __shared__ int rs[CLS_CAP];
    __shared__ float snm[CLS_CAP];
    __shared__ float sneg[CLS_CAP];
    __shared__ float ssum[CLS_CAP];
    int t = threadIdx.x;
    int c = min(cls_cnt[cls], CLS_CAP);
    if (t < CLS_CAP) ssum[t] = 0.0f;
    if (t < c) rs[t] = cls_rows[cls * CLS_CAP + t];
    __syncthreads();
    // reduce the 64 neg partials per row; 8 lanes per row for load parallelism
    {
        int l = t & 7;
        for (int rr = t >> 3; rr < c; rr += 32) {
            int row = rs[rr];
            float s = 0.0f, m = -__builtin_inff();
#pragma unroll
            for (int k = 0; k < 8; ++k) {
                s += part_sum[(size_t)(l * 8 + k) * B_SIZE + row];
                m = fmaxf(m, part_max[(size_t)(l * 8 + k) * B_SIZE + row]);
            }
            s += __shfl_xor(s, 1, 64); m = fmaxf(m, __shfl_xor(m, 1, 64));
            s += __shfl_xor(s, 2, 64); m = fmaxf(m, __shfl_xor(m, 2, 64));
            s += __shfl_xor(s, 4, 64); m = fmaxf(m, __shfl_xor(m, 4, 64));
            if (l == 0) { sneg[rr] = s; snm[rr] = m; }
        }
    }
    __syncthreads();
    int np = c * (c - 1) / 2;
    if (np <= PCAP) {
        for (int p = t; p < np; p += 256) {
            float s = psims[cls * PCAP + p];
            int a, b; pair_decode(p, a, b);
            float e = __expf(-ALPHA * (s - BASE));
            if (s - MARGIN < snm[a]) atomicAdd(&ssum[a], e);
            if (s - MARGIN < snm[b]) atomicAdd(&ssum[b], e);
        }
    } else {
        // fallback: recompute dots, 8 lanes per pair
        for (int base = 0; base < np * 8; base += 256) {
            int slot = base + t;
            if (slot < np * 8) {
                int p = slot >> 3, l = slot & 7;
                int a, b; pair_decode(p, a, b);
                const float4* pa = (const float4*)(emb + (size_t)rs[a] * D_SIZE) + l * 8;
                const float4* pb = (const float4*)(emb + (size_t)rs[b] * D_SIZE) + l * 8;
                float s = 0.0f;
#pragma unroll
                for (int k = 0; k < 8; ++k) {
                    float4 x = pa[k], y = pb[k];
                    s = fmaf(x.x, y.x, fmaf(x.y, y.y, fmaf(x.z, y.z, fmaf(x.w, y.w, s))));
                }
                s += __shfl_xor(s, 1, 64);
                s += __shfl_xor(s, 2, 64);
                s += __shfl_xor(s, 4, 64);
                if (l == 0) {
                    float e = __expf(-ALPHA * (s - BASE));
                    if (s - MARGIN < snm[a]) atomicAdd(&ssum[a], e);
                    if (s - MARGIN < snm[b]) atomicAdd(&ssum[b], e);
                }
            }
        }
    }
    __syncthreads();
    // per-class term: rows live on threads 0..c-1 (all in wave 0) -> shfl reduce
    if (t < 64) {
        float term = 0.0f, valid = 0.0f;
        if (t < c) {
            float sp = ssum[t], sn = sneg[t];
            if (sp > 0.0f && sn > 0.0f) {
                term = log1pf(sp) * (1.0f / ALPHA) + log1pf(sn) * (1.0f / BETA);
                valid = 1.0f;
            }
        }
#pragma unroll
        for (int m = 1; m < 64; m <<= 1) {
            term += __shfl_xor(term, m, 64);
            valid += __shfl_xor(valid, m, 64);
        }
        if (t == 0) { cls_term[cls] = term; cls_valid[cls] = valid; }
    }
}

// ---- K4: fold 1024 class terms -> out ----
__global__ __launch_bounds__(256) void finalize_kernel(
    const float* __restrict__ cls_term, const float* __restrict__ cls_valid,
    float* __restrict__ out) {
    __shared__ float st[256];
    __shared__ float sc[256];
    int t = threadIdx.x;
    float tot = 0.0f, cnt = 0.0f;
#pragma unroll
    for (int i = 0; i < N_CLS / 256; ++i) {
        tot += cls_term[i * 256 + t];
        cnt += cls_valid[i * 256 + t];
    }
    st[t] = tot; sc[t] = cnt;
    __syncthreads();
    for (int s = 128; s > 0; s >>= 1) {
        if (t < s) { st[t] += st[t + s]; sc[t] += sc[t + s]; }
        __syncthreads();
    }
    if (t == 0) out[0] = st[0] / fmaxf(sc[0], 1.0f);
}

extern "C" void kernel_launch(void* const* d_in, const int* in_sizes, int n_in,
                              void* d_out, int out_size, void* d_ws, size_t ws_size,
                              hipStream_t stream) {
    const float* emb = (const float*)d_in[0];
    const int* labels = (const int*)d_in[1];
    float* out = (float*)d_out;

    // ws: embb 4MB | part_sum 2MB | part_max 2MB | psims 1MB | cls_rows 256KB |
    //     pos_min 32KB | cls_term 4KB | cls_valid 4KB | cls_cnt 4KB
    unsigned short* embb = (unsigned short*)d_ws;
    float* part_sum = (float*)(embb + (size_t)B_SIZE * D_SIZE);
    float* part_max = part_sum + (size_t)NT * B_SIZE;
    float* psims = part_max + (size_t)NT * B_SIZE;
    int* cls_rows = (int*)(psims + (size_t)N_CLS * PCAP);
    float* pos_min = (float*)(cls_rows + N_CLS * CLS_CAP);
    float* cls_term = pos_min + B_SIZE;
    float* cls_valid = cls_term + N_CLS;
    int* cls_cnt = (int*)(cls_valid + N_CLS);

    conv_pos_kernel<<<dim3(N_CLS + NCONV), dim3(256), 0, stream>>>(
        emb, labels, embb, pos_min, psims, cls_cnt, cls_rows);
    neg_kernel<<<dim3(NPAIR), dim3(256), 0, stream>>>(
        embb, labels, pos_min, part_sum, part_max);
    final_kernel<<<dim3(N_CLS), dim3(256), 0, stream>>>(
        emb, cls_cnt, cls_rows, psims, part_sum, part_max, cls_term, cls_valid);
    finalize_kernel<<<dim3(1), dim3(256), 0, stream>>>(cls_term, cls_valid, out);
}

// Round 7
// 149.910 us; speedup vs baseline: 1.1637x; 1.0690x over previous
//
#include <hip/hip_runtime.h>
#include <math.h>

#define B_SIZE 8192
#define D_SIZE 256
#define N_CLS 1024
#define CLS_CAP 64
#define PCAP 256
#define ALPHA 2.0f
#define BETA 50.0f
#define BASE 0.5f
#define MARGIN 0.1f

// neg GEMM tiling: 128x128 tile, BK=32 double-buffered LDS (32 KB), 4 waves
// (r2-proven skeleton, 45.9 us). Single tile per block (r6's 2-tile variant
// spilled: WRITE_SIZE 4.1->84.8 MB). Only delta vs r2: the branch-free
// sentinel epilogue (verified absmax 0.0 in r6) + XCD swizzle (r3-proven).
#define TM 128
#define TK 32
#define NT (B_SIZE / TM)            // 64 tiles per dim
#define NBLK (NT * (NT + 1) / 2)    // 2080 triangular tiles
#define NCONV (B_SIZE * D_SIZE / 1024)   // 2048 convert blocks

typedef __attribute__((ext_vector_type(8))) __bf16 bf16x8;
typedef __attribute__((ext_vector_type(4))) float f32x4;

__device__ __forceinline__ unsigned int enc_f32(float f) {
    unsigned int u = __float_as_uint(f);
    return (u & 0x80000000u) ? ~u : (u | 0x80000000u);
}
__device__ __forceinline__ float dec_f32(unsigned int e) {
    unsigned int u = (e & 0x80000000u) ? (e ^ 0x80000000u) : ~e;
    return __uint_as_float(u);
}

__device__ __forceinline__ unsigned short f2bf(float x) {
    unsigned int u = __float_as_uint(x);
    u += 0x7FFFu + ((u >> 16) & 1u);   // RNE
    return (unsigned short)(u >> 16);
}

__device__ __forceinline__ void glds16(const unsigned short* g, const unsigned char* l) {
    __builtin_amdgcn_global_load_lds((const __attribute__((address_space(1))) void*)g,
                                     (__attribute__((address_space(3))) void*)l, 16, 0, 0);
}

// fast 2^x: v_exp_f32 directly (HIP has no __exp2f; glibc macro collision)
__device__ __forceinline__ float fexp2(float x) {
    return __builtin_amdgcn_exp2f(x);
}

// DPP lane-XOR within 16 lanes (VALU pipe, low latency); bit-identical to
// the __shfl_xor butterfly (group totals lane-replicated at each step).
template <int C>
__device__ __forceinline__ float dppx(float x) {
    return __builtin_bit_cast(float, __builtin_amdgcn_update_dpp(
        0, __builtin_bit_cast(int, x), C, 0xF, 0xF, true));
}
__device__ __forceinline__ void red16(float& s, float& m) {
    s += dppx<0xB1>(s);  m = fmaxf(m, dppx<0xB1>(m));
    s += dppx<0x4E>(s);  m = fmaxf(m, dppx<0x4E>(m));
    s += dppx<0x141>(s); m = fmaxf(m, dppx<0x141>(m));
    s += dppx<0x140>(s); m = fmaxf(m, dppx<0x140>(m));
}

// decode unordered pair index p -> (a, b), 0 <= b < a
__device__ __forceinline__ void pair_decode(int p, int& a, int& b) {
    a = (int)((1.0f + sqrtf(1.0f + 8.0f * (float)p)) * 0.5f);
    while (a * (a - 1) / 2 > p) --a;
    while ((a + 1) * a / 2 <= p) ++a;
    b = p - a * (a - 1) / 2;
}

// ---- K1: fused class-blocks (0..N_CLS) + convert blocks (N_CLS..) ----
__global__ __launch_bounds__(256) void conv_pos_kernel(
    const float* __restrict__ emb, const int* __restrict__ labels,
    unsigned short* __restrict__ embb,
    float* __restrict__ pos_min, float* __restrict__ psims,
    int* __restrict__ cls_cnt, int* __restrict__ cls_rows) {
    int t = threadIdx.x;
    if (blockIdx.x >= N_CLS) {
        int i = ((blockIdx.x - N_CLS) * 256 + t) * 4;
        float4 v = *(const float4*)(&emb[i]);
        ushort4 o;
        o.x = f2bf(v.x); o.y = f2bf(v.y); o.z = f2bf(v.z); o.w = f2bf(v.w);
        *(ushort4*)(&embb[i]) = o;
        return;
    }
    int cls = blockIdx.x;
    __shared__ int rs[CLS_CAP];
    __shared__ unsigned int smin[CLS_CAP];
    __shared__ int lcnt;
    if (t == 0) lcnt = 0;
    if (t < CLS_CAP) smin[t] = 0xFF800000u;  // enc(+inf)
    __syncthreads();
    const int4* lab4 = (const int4*)labels;
    for (int i = t; i < B_SIZE / 4; i += 256) {
        int4 L = lab4[i];
        if (L.x == cls) { int p = atomicAdd(&lcnt, 1); if (p < CLS_CAP) rs[p] = 4 * i; }
        if (L.y == cls) { int p = atomicAdd(&lcnt, 1); if (p < CLS_CAP) rs[p] = 4 * i + 1; }
        if (L.z == cls) { int p = atomicAdd(&lcnt, 1); if (p < CLS_CAP) rs[p] = 4 * i + 2; }
        if (L.w == cls) { int p = atomicAdd(&lcnt, 1); if (p < CLS_CAP) rs[p] = 4 * i + 3; }
    }
    __syncthreads();
    int c = min(lcnt, CLS_CAP);
    if (t == 0) cls_cnt[cls] = c;
    if (t < c) cls_rows[cls * CLS_CAP + t] = rs[t];
    int np = c * (c - 1) / 2;
    for (int base = 0; base < np * 8; base += 256) {
        int slot = base + t;
        if (slot < np * 8) {
            int p = slot >> 3, l = slot & 7;   // 8 aligned lanes per pair
            int a, b; pair_decode(p, a, b);
            const float4* pa = (const float4*)(emb + (size_t)rs[a] * D_SIZE) + l * 8;
            const float4* pb = (const float4*)(emb + (size_t)rs[b] * D_SIZE) + l * 8;
            float s = 0.0f;
#pragma unroll
            for (int k = 0; k < 8; ++k) {
                float4 x = pa[k], y = pb[k];
                s = fmaf(x.x, y.x, fmaf(x.y, y.y, fmaf(x.z, y.z, fmaf(x.w, y.w, s))));
            }
            s += __shfl_xor(s, 1, 64);
            s += __shfl_xor(s, 2, 64);
            s += __shfl_xor(s, 4, 64);
            if (l == 0) {
                if (p < PCAP) psims[cls * PCAP + p] = s;
                unsigned int e = enc_f32(s);
                atomicMin(&smin[a], e);
                atomicMin(&smin[b], e);
            }
        }
    }
    __syncthreads();
    if (t < c) pos_min[rs[t]] = dec_f32(smin[t]);
}

// ---- K2: the ONE GEMM (triangular tiles), LDS = exactly 32 KB ----
// part[k*B + row]: m-side writes k=bj (bj>=bi), n-side k=bi (bi<bj).
// C/D layout (16x16x32): col = lane&15, row = (lane>>4)*4 + reg  [m89/m91]
__global__ __launch_bounds__(256, 4) void neg_kernel(
    const unsigned short* __restrict__ embb, const int* __restrict__ labels,
    const float* __restrict__ pos_min,
    float* __restrict__ part_sum, float* __restrict__ part_max)
{
    // XCD-aware bijective swizzle (2080 % 8 == 0), then triangular decode
    int bt = (blockIdx.x & 7) * (NBLK >> 3) + (blockIdx.x >> 3);
    int bi = 0, rem = bt;
    while (rem >= (NT - bi)) { rem -= (NT - bi); ++bi; }
    const int bj = bi + rem;
    const int m0 = bi * TM, n0 = bj * TM;
    const bool isdiag = (bi == bj);

    const int tid = threadIdx.x;
    const int lane = tid & 63;
    const int w = tid >> 6;
    const int wm = w >> 1, wn = w & 1;

    __shared__ unsigned char As[2][TM * 64];
    __shared__ unsigned char Bs[2][TM * 64];

    const unsigned short* gA[2];
    const unsigned short* gB[2];
    int lofs[2];
#pragma unroll
    for (int s = 0; s < 2; ++s) {
        int r = w * 32 + s * 16 + (lane >> 2);
        int c = (lane & 3) ^ ((r >> 1) & 3);
        gA[s] = embb + (size_t)(m0 + r) * D_SIZE + c * 8;
        gB[s] = embb + (size_t)(n0 + r) * D_SIZE + c * 8;
        lofs[s] = (w * 32 + s * 16) * 64;
    }
#pragma unroll
    for (int s = 0; s < 2; ++s) { glds16(gA[s], As[0] + lofs[s]); glds16(gB[s], Bs[0] + lofs[s]); }

    const int col = lane & 15;
    const int quad = lane >> 4;
    // swizzle XOR term depends only on col -> single base per matrix,
    // f advances by a compile-time +1024 (folds into ds_read offset imm)
    const int xsw = (quad ^ ((col >> 1) & 3)) * 16;
    const int aoff0 = (wm * 64 + col) * 64 + xsw;
    const int boff0 = (wn * 64 + col) * 64 + xsw;

    f32x4 acc[4][4];
#pragma unroll
    for (int fi = 0; fi < 4; ++fi)
#pragma unroll
        for (int fj = 0; fj < 4; ++fj)
            acc[fi][fj] = (f32x4){0.0f, 0.0f, 0.0f, 0.0f};

#pragma unroll
    for (int it = 0; it < D_SIZE / TK; ++it) {
        const int st = it & 1;
        __syncthreads();   // stage st's staging complete
        if (it + 1 < D_SIZE / TK) {
            const int k1 = (it + 1) * TK;
#pragma unroll
            for (int s = 0; s < 2; ++s) {
                glds16(gA[s] + k1, As[st ^ 1] + lofs[s]);
                glds16(gB[s] + k1, Bs[st ^ 1] + lofs[s]);
            }
        }
        bf16x8 af[4], bf[4];
#pragma unroll
        for (int f = 0; f < 4; ++f) {
            af[f] = __builtin_bit_cast(bf16x8, *(const uint4*)(As[st] + aoff0 + f * 1024));
            bf[f] = __builtin_bit_cast(bf16x8, *(const uint4*)(Bs[st] + boff0 + f * 1024));
        }
#pragma unroll
        for (int fi = 0; fi < 4; ++fi)
#pragma unroll
            for (int fj = 0; fj < 4; ++fj)
                acc[fi][fj] = __builtin_amdgcn_mfma_f32_16x16x32_bf16(
                    af[fi], bf[fj], acc[fi][fj], 0, 0, 0);
    }

    // ---- branch-free sentinel epilogue (verified absmax 0.0 in r6) ----
    // sm = diff-class ? s : -3 (sims in [-1,1]); exp2(fma(-3,K1,K2)) -> 0,
    // so masked elements add 0 to sums and -3 < any real sim for maxes.
    const float K1 = 72.13475204444817f;   /* BETA*log2(e) */
    const float K2 = -36.067376022224085f; /* -BETA*BASE*log2(e) */
    int ljv[4]; float pmc[4], nsn[4], nmx[4];
#pragma unroll
    for (int fj = 0; fj < 4; ++fj) {
        int cl = wn * 64 + fj * 16 + col;
        ljv[fj] = labels[n0 + cl];
        pmc[fj] = pos_min[n0 + cl] - MARGIN;
        nsn[fj] = 0.0f;
        nmx[fj] = -3.0f;
    }

#pragma unroll
    for (int fi = 0; fi < 4; ++fi) {
        int gi0 = m0 + wm * 64 + fi * 16 + quad * 4;
        int lir[4]; float pmr[4], msn[4], mmx[4];
#pragma unroll
        for (int r = 0; r < 4; ++r) {
            lir[r] = labels[gi0 + r];
            pmr[r] = pos_min[gi0 + r] - MARGIN;
            msn[r] = 0.0f;
            mmx[r] = -3.0f;
        }
#pragma unroll
        for (int fj = 0; fj < 4; ++fj) {
#pragma unroll
            for (int r = 0; r < 4; ++r) {
                float s = acc[fi][fj][r];
                float sm = (lir[r] != ljv[fj]) ? s : -3.0f;
                float e = fexp2(fmaf(sm, K1, K2));
                mmx[r] = fmaxf(mmx[r], sm);
                nmx[fj] = fmaxf(nmx[fj], sm);
                msn[r] += (sm > pmr[r]) ? e : 0.0f;
                nsn[fj] += (sm > pmc[fj]) ? e : 0.0f;
            }
        }
        // 16-lane (col) reduction via DPP — VALU, no LDS pipe
#pragma unroll
        for (int r = 0; r < 4; ++r) red16(msn[r], mmx[r]);
        if (col == 0) {
            *(float4*)(&part_sum[(size_t)bj * B_SIZE + gi0]) =
                make_float4(msn[0], msn[1], msn[2], msn[3]);
            *(float4*)(&part_max[(size_t)bj * B_SIZE + gi0]) =
                make_float4(mmx[0], mmx[1], mmx[2], mmx[3]);
        }
    }
    if (!isdiag) {
#pragma unroll
        for (int m = 16; m < 64; m <<= 1) {
#pragma unroll
            for (int fj = 0; fj < 4; ++fj) {
                nsn[fj] += __shfl_xor(nsn[fj], m, 64);
                nmx[fj] = fmaxf(nmx[fj], __shfl_xor(nmx[fj], m, 64));
            }
        }
        if (quad == 0) {
#pragma unroll
            for (int fj = 0; fj < 4; ++fj) {
                int gj = n0 + wn * 64 + fj * 16 + col;
                part_sum[(size_t)bi * B_SIZE + gj] = nsn[fj];
                part_max[(size_t)bi * B_SIZE + gj] = nmx[fj];
            }
        }
    }
}

// ---- K3: per-class reduce partials (8 lanes/row) + sum_pos + per-class term ----
__global__ __launch_bounds__(256) void final_kernel(
    const float* __restrict__ emb, const int* __restrict__ cls_cnt,
    const int* __restrict__ cls_rows, const float* __restrict__ psims,
    const float* __restrict__ part_sum, const float* __restrict__ part_max,
    float* __restrict__ cls_term, float* __restrict__ cls_valid) {
    int cls = blockIdx.x;
    __shared__ int rs[CLS_CAP];
    __shared__ float snm[CLS_CAP];
    __shared__ float sneg[CLS_CAP];
    __shared__ float ssum[CLS_CAP];
    int t = threadIdx.x;
    int c = min(cls_cnt[cls], CLS_CAP);
    if (t < CLS_CAP) ssum[t] = 0.0f;
    if (t < c) rs[t] = cls_rows[cls * CLS_CAP + t];
    __syncthreads();
    // reduce the 64 neg partials per row; 8 lanes per row for load parallelism
    {
        int l = t & 7;
        for (int rr = t >> 3; rr < c; rr += 32) {
            int row = rs[rr];
            float s = 0.0f, m = -__builtin_inff();
#pragma unroll
            for (int k = 0; k < 8; ++k) {
                s += part_sum[(size_t)(l * 8 + k) * B_SIZE + row];
                m = fmaxf(m, part_max[(size_t)(l * 8 + k) * B_SIZE + row]);
            }
            s += __shfl_xor(s, 1, 64); m = fmaxf(m, __shfl_xor(m, 1, 64));
            s += __shfl_xor(s, 2, 64); m = fmaxf(m, __shfl_xor(m, 2, 64));
            s += __shfl_xor(s, 4, 64); m = fmaxf(m, __shfl_xor(m, 4, 64));
            if (l == 0) { sneg[rr] = s; snm[rr] = m; }
        }
    }
    __syncthreads();
    int np = c * (c - 1) / 2;
    if (np <= PCAP) {
        for (int p = t; p < np; p += 256) {
            float s = psims[cls * PCAP + p];
            int a, b; pair_decode(p, a, b);
            float e = __expf(-ALPHA * (s - BASE));
            if (s - MARGIN < snm[a]) atomicAdd(&ssum[a], e);
            if (s - MARGIN < snm[b]) atomicAdd(&ssum[b], e);
        }
    } else {
        // fallback: recompute dots, 8 lanes per pair
        for (int base = 0; base < np * 8; base += 256) {
            int slot = base + t;
            if (slot < np * 8) {
                int p = slot >> 3, l = slot & 7;
                int a, b; pair_decode(p, a, b);
                const float4* pa = (const float4*)(emb + (size_t)rs[a] * D_SIZE) + l * 8;
                const float4* pb = (const float4*)(emb + (size_t)rs[b] * D_SIZE) + l * 8;
                float s = 0.0f;
#pragma unroll
                for (int k = 0; k < 8; ++k) {
                    float4 x = pa[k], y = pb[k];
                    s = fmaf(x.x, y.x, fmaf(x.y, y.y, fmaf(x.z, y.z, fmaf(x.w, y.w, s))));
                }
                s += __shfl_xor(s, 1, 64);
                s += __shfl_xor(s, 2, 64);
                s += __shfl_xor(s, 4, 64);
                if (l == 0) {
                    float e = __expf(-ALPHA * (s - BASE));
                    if (s - MARGIN < snm[a]) atomicAdd(&ssum[a], e);
                    if (s - MARGIN < snm[b]) atomicAdd(&ssum[b], e);
                }
            }
        }
    }
    __syncthreads();
    // per-class term: rows live on threads 0..c-1 (all in wave 0) -> shfl reduce
    if (t < 64) {
        float term = 0.0f, valid = 0.0f;
        if (t < c) {
            float sp = ssum[t], sn = sneg[t];
            if (sp > 0.0f && sn > 0.0f) {
                term = log1pf(sp) * (1.0f / ALPHA) + log1pf(sn) * (1.0f / BETA);
                valid = 1.0f;
            }
        }
#pragma unroll
        for (int m = 1; m < 64; m <<= 1) {
            term += __shfl_xor(term, m, 64);
            valid += __shfl_xor(valid, m, 64);
        }
        if (t == 0) { cls_term[cls] = term; cls_valid[cls] = valid; }
    }
}

// ---- K4: fold 1024 class terms -> out ----
__global__ __launch_bounds__(256) void finalize_kernel(
    const float* __restrict__ cls_term, const float* __restrict__ cls_valid,
    float* __restrict__ out) {
    __shared__ float st[256];
    __shared__ float sc[256];
    int t = threadIdx.x;
    float tot = 0.0f, cnt = 0.0f;
#pragma unroll
    for (int i = 0; i < N_CLS / 256; ++i) {
        tot += cls_term[i * 256 + t];
        cnt += cls_valid[i * 256 + t];
    }
    st[t] = tot; sc[t] = cnt;
    __syncthreads();
    for (int s = 128; s > 0; s >>= 1) {
        if (t < s) { st[t] += st[t + s]; sc[t] += sc[t + s]; }
        __syncthreads();
    }
    if (t == 0) out[0] = st[0] / fmaxf(sc[0], 1.0f);
}

extern "C" void kernel_launch(void* const* d_in, const int* in_sizes, int n_in,
                              void* d_out, int out_size, void* d_ws, size_t ws_size,
                              hipStream_t stream) {
    const float* emb = (const float*)d_in[0];
    const int* labels = (const int*)d_in[1];
    float* out = (float*)d_out;

    // ws: embb 4MB | part_sum 2MB | part_max 2MB | psims 1MB | cls_rows 256KB |
    //     pos_min 32KB | cls_term 4KB | cls_valid 4KB | cls_cnt 4KB
    unsigned short* embb = (unsigned short*)d_ws;
    float* part_sum = (float*)(embb + (size_t)B_SIZE * D_SIZE);
    float* part_max = part_sum + (size_t)NT * B_SIZE;
    float* psims = part_max + (size_t)NT * B_SIZE;
    int* cls_rows = (int*)(psims + (size_t)N_CLS * PCAP);
    float* pos_min = (float*)(cls_rows + N_CLS * CLS_CAP);
    float* cls_term = pos_min + B_SIZE;
    float* cls_valid = cls_term + N_CLS;
    int* cls_cnt = (int*)(cls_valid + N_CLS);

    conv_pos_kernel<<<dim3(N_CLS + NCONV), dim3(256), 0, stream>>>(
        emb, labels, embb, pos_min, psims, cls_cnt, cls_rows);
    neg_kernel<<<dim3(NBLK), dim3(256), 0, stream>>>(
        embb, labels, pos_min, part_sum, part_max);
    final_kernel<<<dim3(N_CLS), dim3(256), 0, stream>>>(
        emb, cls_cnt, cls_rows, psims, part_sum, part_max, cls_term, cls_valid);
    finalize_kernel<<<dim3(1), dim3(256), 0, stream>>>(cls_term, cls_valid, out);
}

// Round 8
// 143.619 us; speedup vs baseline: 1.2147x; 1.0438x over previous
//
#include <hip/hip_runtime.h>
#include <math.h>

#define B_SIZE 8192
#define D_SIZE 256
#define N_CLS 1024
#define CLS_CAP 64
#define PCAP 256
#define ALPHA 2.0f
#define BETA 50.0f
#define BASE 0.5f
#define MARGIN 0.1f

// neg GEMM tiling: 128x128 tile, BK=32 double-buffered LDS (32 KB), 4 waves
// (r2-proven skeleton). Sentinel epilogue with per-fj sched_barrier(0)
// fences: without them the scheduler batches all 64 fexp2 ops -> ~64 live
// temps -> scratch spill under the 128-reg cap (r7: WRITE_SIZE 93 MB).
#define TM 128
#define TK 32
#define NT (B_SIZE / TM)            // 64 tiles per dim
#define NBLK (NT * (NT + 1) / 2)    // 2080 triangular tiles
#define NCONV (B_SIZE * D_SIZE / 1024)   // 2048 convert blocks

typedef __attribute__((ext_vector_type(8))) __bf16 bf16x8;
typedef __attribute__((ext_vector_type(4))) float f32x4;

__device__ __forceinline__ unsigned int enc_f32(float f) {
    unsigned int u = __float_as_uint(f);
    return (u & 0x80000000u) ? ~u : (u | 0x80000000u);
}
__device__ __forceinline__ float dec_f32(unsigned int e) {
    unsigned int u = (e & 0x80000000u) ? (e ^ 0x80000000u) : ~e;
    return __uint_as_float(u);
}

__device__ __forceinline__ unsigned short f2bf(float x) {
    unsigned int u = __float_as_uint(x);
    u += 0x7FFFu + ((u >> 16) & 1u);   // RNE
    return (unsigned short)(u >> 16);
}

__device__ __forceinline__ void glds16(const unsigned short* g, const unsigned char* l) {
    __builtin_amdgcn_global_load_lds((const __attribute__((address_space(1))) void*)g,
                                     (__attribute__((address_space(3))) void*)l, 16, 0, 0);
}

// fast 2^x: v_exp_f32 directly (HIP has no __exp2f; glibc macro collision)
__device__ __forceinline__ float fexp2(float x) {
    return __builtin_amdgcn_exp2f(x);
}

// DPP lane-XOR within 16 lanes (VALU pipe, low latency); bit-identical to
// the __shfl_xor butterfly (group totals lane-replicated at each step).
template <int C>
__device__ __forceinline__ float dppx(float x) {
    return __builtin_bit_cast(float, __builtin_amdgcn_update_dpp(
        0, __builtin_bit_cast(int, x), C, 0xF, 0xF, true));
}
__device__ __forceinline__ void red16(float& s, float& m) {
    s += dppx<0xB1>(s);  m = fmaxf(m, dppx<0xB1>(m));
    s += dppx<0x4E>(s);  m = fmaxf(m, dppx<0x4E>(m));
    s += dppx<0x141>(s); m = fmaxf(m, dppx<0x141>(m));
    s += dppx<0x140>(s); m = fmaxf(m, dppx<0x140>(m));
}

// decode unordered pair index p -> (a, b), 0 <= b < a
__device__ __forceinline__ void pair_decode(int p, int& a, int& b) {
    a = (int)((1.0f + sqrtf(1.0f + 8.0f * (float)p)) * 0.5f);
    while (a * (a - 1) / 2 > p) --a;
    while ((a + 1) * a / 2 <= p) ++a;
    b = p - a * (a - 1) / 2;
}

// ---- K1: fused class-blocks (0..N_CLS) + convert blocks (N_CLS..) ----
__global__ __launch_bounds__(256) void conv_pos_kernel(
    const float* __restrict__ emb, const int* __restrict__ labels,
    unsigned short* __restrict__ embb,
    float* __restrict__ pos_min, float* __restrict__ psims,
    int* __restrict__ cls_cnt, int* __restrict__ cls_rows) {
    int t = threadIdx.x;
    if (blockIdx.x >= N_CLS) {
        int i = ((blockIdx.x - N_CLS) * 256 + t) * 4;
        float4 v = *(const float4*)(&emb[i]);
        ushort4 o;
        o.x = f2bf(v.x); o.y = f2bf(v.y); o.z = f2bf(v.z); o.w = f2bf(v.w);
        *(ushort4*)(&embb[i]) = o;
        return;
    }
    int cls = blockIdx.x;
    __shared__ int rs[CLS_CAP];
    __shared__ unsigned int smin[CLS_CAP];
    __shared__ int lcnt;
    if (t == 0) lcnt = 0;
    if (t < CLS_CAP) smin[t] = 0xFF800000u;  // enc(+inf)
    __syncthreads();
    const int4* lab4 = (const int4*)labels;
    for (int i = t; i < B_SIZE / 4; i += 256) {
        int4 L = lab4[i];
        if (L.x == cls) { int p = atomicAdd(&lcnt, 1); if (p < CLS_CAP) rs[p] = 4 * i; }
        if (L.y == cls) { int p = atomicAdd(&lcnt, 1); if (p < CLS_CAP) rs[p] = 4 * i + 1; }
        if (L.z == cls) { int p = atomicAdd(&lcnt, 1); if (p < CLS_CAP) rs[p] = 4 * i + 2; }
        if (L.w == cls) { int p = atomicAdd(&lcnt, 1); if (p < CLS_CAP) rs[p] = 4 * i + 3; }
    }
    __syncthreads();
    int c = min(lcnt, CLS_CAP);
    if (t == 0) cls_cnt[cls] = c;
    if (t < c) cls_rows[cls * CLS_CAP + t] = rs[t];
    int np = c * (c - 1) / 2;
    for (int base = 0; base < np * 8; base += 256) {
        int slot = base + t;
        if (slot < np * 8) {
            int p = slot >> 3, l = slot & 7;   // 8 aligned lanes per pair
            int a, b; pair_decode(p, a, b);
            const float4* pa = (const float4*)(emb + (size_t)rs[a] * D_SIZE) + l * 8;
            const float4* pb = (const float4*)(emb + (size_t)rs[b] * D_SIZE) + l * 8;
            float s = 0.0f;
#pragma unroll
            for (int k = 0; k < 8; ++k) {
                float4 x = pa[k], y = pb[k];
                s = fmaf(x.x, y.x, fmaf(x.y, y.y, fmaf(x.z, y.z, fmaf(x.w, y.w, s))));
            }
            s += __shfl_xor(s, 1, 64);
            s += __shfl_xor(s, 2, 64);
            s += __shfl_xor(s, 4, 64);
            if (l == 0) {
                if (p < PCAP) psims[cls * PCAP + p] = s;
                unsigned int e = enc_f32(s);
                atomicMin(&smin[a], e);
                atomicMin(&smin[b], e);
            }
        }
    }
    __syncthreads();
    if (t < c) pos_min[rs[t]] = dec_f32(smin[t]);
}

// ---- K2: the ONE GEMM (triangular tiles), LDS = exactly 32 KB ----
// part[k*B + row]: m-side writes k=bj (bj>=bi), n-side k=bi (bi<bj).
// C/D layout (16x16x32): col = lane&15, row = (lane>>4)*4 + reg  [m89/m91]
__global__ __launch_bounds__(256, 4) void neg_kernel(
    const unsigned short* __restrict__ embb, const int* __restrict__ labels,
    const float* __restrict__ pos_min,
    float* __restrict__ part_sum, float* __restrict__ part_max)
{
    // XCD-aware bijective swizzle (2080 % 8 == 0), then triangular decode
    int bt = (blockIdx.x & 7) * (NBLK >> 3) + (blockIdx.x >> 3);
    int bi = 0, rem = bt;
    while (rem >= (NT - bi)) { rem -= (NT - bi); ++bi; }
    const int bj = bi + rem;
    const int m0 = bi * TM, n0 = bj * TM;
    const bool isdiag = (bi == bj);

    const int tid = threadIdx.x;
    const int lane = tid & 63;
    const int w = tid >> 6;
    const int wm = w >> 1, wn = w & 1;

    __shared__ unsigned char As[2][TM * 64];
    __shared__ unsigned char Bs[2][TM * 64];

    const unsigned short* gA[2];
    const unsigned short* gB[2];
    int lofs[2];
#pragma unroll
    for (int s = 0; s < 2; ++s) {
        int r = w * 32 + s * 16 + (lane >> 2);
        int c = (lane & 3) ^ ((r >> 1) & 3);
        gA[s] = embb + (size_t)(m0 + r) * D_SIZE + c * 8;
        gB[s] = embb + (size_t)(n0 + r) * D_SIZE + c * 8;
        lofs[s] = (w * 32 + s * 16) * 64;
    }
#pragma unroll
    for (int s = 0; s < 2; ++s) { glds16(gA[s], As[0] + lofs[s]); glds16(gB[s], Bs[0] + lofs[s]); }

    const int col = lane & 15;
    const int quad = lane >> 4;
    // swizzle XOR term depends only on col -> single base per matrix,
    // f advances by a compile-time +1024 (folds into ds_read offset imm)
    const int xsw = (quad ^ ((col >> 1) & 3)) * 16;
    const int aoff0 = (wm * 64 + col) * 64 + xsw;
    const int boff0 = (wn * 64 + col) * 64 + xsw;

    f32x4 acc[4][4];
#pragma unroll
    for (int fi = 0; fi < 4; ++fi)
#pragma unroll
        for (int fj = 0; fj < 4; ++fj)
            acc[fi][fj] = (f32x4){0.0f, 0.0f, 0.0f, 0.0f};

#pragma unroll
    for (int it = 0; it < D_SIZE / TK; ++it) {
        const int st = it & 1;
        __syncthreads();   // stage st's staging complete
        if (it + 1 < D_SIZE / TK) {
            const int k1 = (it + 1) * TK;
#pragma unroll
            for (int s = 0; s < 2; ++s) {
                glds16(gA[s] + k1, As[st ^ 1] + lofs[s]);
                glds16(gB[s] + k1, Bs[st ^ 1] + lofs[s]);
            }
        }
        bf16x8 af[4], bf[4];
#pragma unroll
        for (int f = 0; f < 4; ++f) {
            af[f] = __builtin_bit_cast(bf16x8, *(const uint4*)(As[st] + aoff0 + f * 1024));
            bf[f] = __builtin_bit_cast(bf16x8, *(const uint4*)(Bs[st] + boff0 + f * 1024));
        }
#pragma unroll
        for (int fi = 0; fi < 4; ++fi)
#pragma unroll
            for (int fj = 0; fj < 4; ++fj)
                acc[fi][fj] = __builtin_amdgcn_mfma_f32_16x16x32_bf16(
                    af[fi], bf[fj], acc[fi][fj], 0, 0, 0);
    }

    // ---- branch-free sentinel epilogue, sched-fenced per fj-group ----
    // sm = diff-class ? s : -3 (sims in [-1,1]); exp2(fma(-3,K1,K2)) -> 0,
    // so masked elements add 0 to sums and -3 < any real sim for maxes.
    // sched_barrier(0) after each fj-group keeps <=4 exp temps live
    // (without it the scheduler batches all 64 exps -> spill, r7).
    const float K1 = 72.13475204444817f;   /* BETA*log2(e) */
    const float K2 = -36.067376022224085f; /* -BETA*BASE*log2(e) */
    int ljv[4]; float pmc[4], nsn[4], nmx[4];
#pragma unroll
    for (int fj = 0; fj < 4; ++fj) {
        int cl = wn * 64 + fj * 16 + col;
        ljv[fj] = labels[n0 + cl];
        pmc[fj] = pos_min[n0 + cl] - MARGIN;
        nsn[fj] = 0.0f;
        nmx[fj] = -3.0f;
    }

#pragma unroll
    for (int fi = 0; fi < 4; ++fi) {
        int gi0 = m0 + wm * 64 + fi * 16 + quad * 4;
        int lir[4]; float pmr[4], msn[4], mmx[4];
#pragma unroll
        for (int r = 0; r < 4; ++r) {
            lir[r] = labels[gi0 + r];
            pmr[r] = pos_min[gi0 + r] - MARGIN;
            msn[r] = 0.0f;
            mmx[r] = -3.0f;
        }
        __builtin_amdgcn_sched_barrier(0);
#pragma unroll
        for (int fj = 0; fj < 4; ++fj) {
#pragma unroll
            for (int r = 0; r < 4; ++r) {
                float s = acc[fi][fj][r];
                float sm = (lir[r] != ljv[fj]) ? s : -3.0f;
                float e = fexp2(fmaf(sm, K1, K2));
                mmx[r] = fmaxf(mmx[r], sm);
                nmx[fj] = fmaxf(nmx[fj], sm);
                msn[r] += (sm > pmr[r]) ? e : 0.0f;
                nsn[fj] += (sm > pmc[fj]) ? e : 0.0f;
            }
            __builtin_amdgcn_sched_barrier(0);
        }
        // 16-lane (col) reduction via DPP — VALU, no LDS pipe
#pragma unroll
        for (int r = 0; r < 4; ++r) red16(msn[r], mmx[r]);
        if (col == 0) {
            *(float4*)(&part_sum[(size_t)bj * B_SIZE + gi0]) =
                make_float4(msn[0], msn[1], msn[2], msn[3]);
            *(float4*)(&part_max[(size_t)bj * B_SIZE + gi0]) =
                make_float4(mmx[0], mmx[1], mmx[2], mmx[3]);
        }
        __builtin_amdgcn_sched_barrier(0);
    }
    if (!isdiag) {
#pragma unroll
        for (int m = 16; m < 64; m <<= 1) {
#pragma unroll
            for (int fj = 0; fj < 4; ++fj) {
                nsn[fj] += __shfl_xor(nsn[fj], m, 64);
                nmx[fj] = fmaxf(nmx[fj], __shfl_xor(nmx[fj], m, 64));
            }
        }
        if (quad == 0) {
#pragma unroll
            for (int fj = 0; fj < 4; ++fj) {
                int gj = n0 + wn * 64 + fj * 16 + col;
                part_sum[(size_t)bi * B_SIZE + gj] = nsn[fj];
                part_max[(size_t)bi * B_SIZE + gj] = nmx[fj];
            }
        }
    }
}

// ---- K3: per-class reduce partials (8 lanes/row) + sum_pos + per-class term ----
__global__ __launch_bounds__(256) void final_kernel(
    const float* __restrict__ emb, const int* __restrict__ cls_cnt,
    const int* __restrict__ cls_rows, const float* __restrict__ psims,
    const float* __restrict__ part_sum, const float* __restrict__ part_max,
    float* __restrict__ cls_term, float* __restrict__ cls_valid) {
    int cls = blockIdx.x;
    __shared__ int rs[CLS_CAP];
    __shared__ float snm[CLS_CAP];
    __shared__ float sneg[CLS_CAP];
    __shared__ float ssum[CLS_CAP];
    int t = threadIdx.x;
    int c = min(cls_cnt[cls], CLS_CAP);
    if (t < CLS_CAP) ssum[t] = 0.0f;
    if (t < c) rs[t] = cls_rows[cls * CLS_CAP + t];
    __syncthreads();
    // reduce the 64 neg partials per row; 8 lanes per row for load parallelism
    {
        int l = t & 7;
        for (int rr = t >> 3; rr < c; rr += 32) {
            int row = rs[rr];
            float s = 0.0f, m = -__builtin_inff();
#pragma unroll
            for (int k = 0; k < 8; ++k) {
                s += part_sum[(size_t)(l * 8 + k) * B_SIZE + row];
                m = fmaxf(m, part_max[(size_t)(l * 8 + k) * B_SIZE + row]);
            }
            s += __shfl_xor(s, 1, 64); m = fmaxf(m, __shfl_xor(m, 1, 64));
            s += __shfl_xor(s, 2, 64); m = fmaxf(m, __shfl_xor(m, 2, 64));
            s += __shfl_xor(s, 4, 64); m = fmaxf(m, __shfl_xor(m, 4, 64));
            if (l == 0) { sneg[rr] = s; snm[rr] = m; }
        }
    }
    __syncthreads();
    int np = c * (c - 1) / 2;
    if (np <= PCAP) {
        for (int p = t; p < np; p += 256) {
            float s = psims[cls * PCAP + p];
            int a, b; pair_decode(p, a, b);
            float e = __expf(-ALPHA * (s - BASE));
            if (s - MARGIN < snm[a]) atomicAdd(&ssum[a], e);
            if (s - MARGIN < snm[b]) atomicAdd(&ssum[b], e);
        }
    } else {
        // fallback: recompute dots, 8 lanes per pair
        for (int base = 0; base < np * 8; base += 256) {
            int slot = base + t;
            if (slot < np * 8) {
                int p = slot >> 3, l = slot & 7;
                int a, b; pair_decode(p, a, b);
                const float4* pa = (const float4*)(emb + (size_t)rs[a] * D_SIZE) + l * 8;
                const float4* pb = (const float4*)(emb + (size_t)rs[b] * D_SIZE) + l * 8;
                float s = 0.0f;
#pragma unroll
                for (int k = 0; k < 8; ++k) {
                    float4 x = pa[k], y = pb[k];
                    s = fmaf(x.x, y.x, fmaf(x.y, y.y, fmaf(x.z, y.z, fmaf(x.w, y.w, s))));
                }
                s += __shfl_xor(s, 1, 64);
                s += __shfl_xor(s, 2, 64);
                s += __shfl_xor(s, 4, 64);
                if (l == 0) {
                    float e = __expf(-ALPHA * (s - BASE));
                    if (s - MARGIN < snm[a]) atomicAdd(&ssum[a], e);
                    if (s - MARGIN < snm[b]) atomicAdd(&ssum[b], e);
                }
            }
        }
    }
    __syncthreads();
    // per-class term: rows live on threads 0..c-1 (all in wave 0) -> shfl reduce
    if (t < 64) {
        float term = 0.0f, valid = 0.0f;
        if (t < c) {
            float sp = ssum[t], sn = sneg[t];
            if (sp > 0.0f && sn > 0.0f) {
                term = log1pf(sp) * (1.0f / ALPHA) + log1pf(sn) * (1.0f / BETA);
                valid = 1.0f;
            }
        }
#pragma unroll
        for (int m = 1; m < 64; m <<= 1) {
            term += __shfl_xor(term, m, 64);
            valid += __shfl_xor(valid, m, 64);
        }
        if (t == 0) { cls_term[cls] = term; cls_valid[cls] = valid; }
    }
}

// ---- K4: fold 1024 class terms -> out ----
__global__ __launch_bounds__(256) void finalize_kernel(
    const float* __restrict__ cls_term, const float* __restrict__ cls_valid,
    float* __restrict__ out) {
    __shared__ float st[256];
    __shared__ float sc[256];
    int t = threadIdx.x;
    float tot = 0.0f, cnt = 0.0f;
#pragma unroll
    for (int i = 0; i < N_CLS / 256; ++i) {
        tot += cls_term[i * 256 + t];
        cnt += cls_valid[i * 256 + t];
    }
    st[t] = tot; sc[t] = cnt;
    __syncthreads();
    for (int s = 128; s > 0; s >>= 1) {
        if (t < s) { st[t] += st[t + s]; sc[t] += sc[t + s]; }
        __syncthreads();
    }
    if (t == 0) out[0] = st[0] / fmaxf(sc[0], 1.0f);
}

extern "C" void kernel_launch(void* const* d_in, const int* in_sizes, int n_in,
                              void* d_out, int out_size, void* d_ws, size_t ws_size,
                              hipStream_t stream) {
    const float* emb = (const float*)d_in[0];
    const int* labels = (const int*)d_in[1];
    float* out = (float*)d_out;

    // ws: embb 4MB | part_sum 2MB | part_max 2MB | psims 1MB | cls_rows 256KB |
    //     pos_min 32KB | cls_term 4KB | cls_valid 4KB | cls_cnt 4KB
    unsigned short* embb = (unsigned short*)d_ws;
    float* part_sum = (float*)(embb + (size_t)B_SIZE * D_SIZE);
    float* part_max = part_sum + (size_t)NT * B_SIZE;
    float* psims = part_max + (size_t)NT * B_SIZE;
    int* cls_rows = (int*)(psims + (size_t)N_CLS * PCAP);
    float* pos_min = (float*)(cls_rows + N_CLS * CLS_CAP);
    float* cls_term = pos_min + B_SIZE;
    float* cls_valid = cls_term + N_CLS;
    int* cls_cnt = (int*)(cls_valid + N_CLS);

    conv_pos_kernel<<<dim3(N_CLS + NCONV), dim3(256), 0, stream>>>(
        emb, labels, embb, pos_min, psims, cls_cnt, cls_rows);
    neg_kernel<<<dim3(NBLK), dim3(256), 0, stream>>>(
        embb, labels, pos_min, part_sum, part_max);
    final_kernel<<<dim3(N_CLS), dim3(256), 0, stream>>>(
        emb, cls_cnt, cls_rows, psims, part_sum, part_max, cls_term, cls_valid);
    finalize_kernel<<<dim3(1), dim3(256), 0, stream>>>(cls_term, cls_valid, out);
}

// Round 9
// 126.916 us; speedup vs baseline: 1.3745x; 1.1316x over previous
//
#include <hip/hip_runtime.h>
#include <math.h>

#define B_SIZE 8192
#define D_SIZE 256
#define N_CLS 1024
#define CLS_CAP 64
#define PCAP 256
#define ALPHA 2.0f
#define BETA 50.0f
#define BASE 0.5f
#define MARGIN 0.1f

// neg GEMM tiling: 128x128 tile, BK=32 double-buffered LDS (32 KB), 4 waves
// (r2-proven skeleton). Sentinel epilogue (verified absmax 0.0). Register
// budget: epilogue live set = 64 acc + ~32 state + temps ~= 130-156 unified,
// which cannot fit the 128-reg cap of (256,4) -> spilled in r7/r8 (93/64 MB
// WRITE). (256,3) gives ~168 regs -> no spill; r2-vs-r3 A/B measured the
// 4th wave/SIMD as neutral (45.9 vs 45.5 us), so occupancy cost ~ 0.
#define TM 128
#define TK 32
#define NT (B_SIZE / TM)            // 64 tiles per dim
#define NBLK (NT * (NT + 1) / 2)    // 2080 triangular tiles
#define NCONV (B_SIZE * D_SIZE / 1024)   // 2048 convert blocks

typedef __attribute__((ext_vector_type(8))) __bf16 bf16x8;
typedef __attribute__((ext_vector_type(4))) float f32x4;

__device__ __forceinline__ unsigned int enc_f32(float f) {
    unsigned int u = __float_as_uint(f);
    return (u & 0x80000000u) ? ~u : (u | 0x80000000u);
}
__device__ __forceinline__ float dec_f32(unsigned int e) {
    unsigned int u = (e & 0x80000000u) ? (e ^ 0x80000000u) : ~e;
    return __uint_as_float(u);
}

__device__ __forceinline__ unsigned short f2bf(float x) {
    unsigned int u = __float_as_uint(x);
    u += 0x7FFFu + ((u >> 16) & 1u);   // RNE
    return (unsigned short)(u >> 16);
}

__device__ __forceinline__ void glds16(const unsigned short* g, const unsigned char* l) {
    __builtin_amdgcn_global_load_lds((const __attribute__((address_space(1))) void*)g,
                                     (__attribute__((address_space(3))) void*)l, 16, 0, 0);
}

// fast 2^x: v_exp_f32 directly (HIP has no __exp2f; glibc macro collision)
__device__ __forceinline__ float fexp2(float x) {
    return __builtin_amdgcn_exp2f(x);
}

// DPP lane-XOR within 16 lanes (VALU pipe, low latency); bit-identical to
// the __shfl_xor butterfly (group totals lane-replicated at each step).
template <int C>
__device__ __forceinline__ float dppx(float x) {
    return __builtin_bit_cast(float, __builtin_amdgcn_update_dpp(
        0, __builtin_bit_cast(int, x), C, 0xF, 0xF, true));
}
__device__ __forceinline__ void red16(float& s, float& m) {
    s += dppx<0xB1>(s);  m = fmaxf(m, dppx<0xB1>(m));
    s += dppx<0x4E>(s);  m = fmaxf(m, dppx<0x4E>(m));
    s += dppx<0x141>(s); m = fmaxf(m, dppx<0x141>(m));
    s += dppx<0x140>(s); m = fmaxf(m, dppx<0x140>(m));
}

// decode unordered pair index p -> (a, b), 0 <= b < a
__device__ __forceinline__ void pair_decode(int p, int& a, int& b) {
    a = (int)((1.0f + sqrtf(1.0f + 8.0f * (float)p)) * 0.5f);
    while (a * (a - 1) / 2 > p) --a;
    while ((a + 1) * a / 2 <= p) ++a;
    b = p - a * (a - 1) / 2;
}

// ---- K1: fused class-blocks (0..N_CLS) + convert blocks (N_CLS..) ----
__global__ __launch_bounds__(256) void conv_pos_kernel(
    const float* __restrict__ emb, const int* __restrict__ labels,
    unsigned short* __restrict__ embb,
    float* __restrict__ pos_min, float* __restrict__ psims,
    int* __restrict__ cls_cnt, int* __restrict__ cls_rows) {
    int t = threadIdx.x;
    if (blockIdx.x >= N_CLS) {
        int i = ((blockIdx.x - N_CLS) * 256 + t) * 4;
        float4 v = *(const float4*)(&emb[i]);
        ushort4 o;
        o.x = f2bf(v.x); o.y = f2bf(v.y); o.z = f2bf(v.z); o.w = f2bf(v.w);
        *(ushort4*)(&embb[i]) = o;
        return;
    }
    int cls = blockIdx.x;
    __shared__ int rs[CLS_CAP];
    __shared__ unsigned int smin[CLS_CAP];
    __shared__ int lcnt;
    if (t == 0) lcnt = 0;
    if (t < CLS_CAP) smin[t] = 0xFF800000u;  // enc(+inf)
    __syncthreads();
    const int4* lab4 = (const int4*)labels;
    for (int i = t; i < B_SIZE / 4; i += 256) {
        int4 L = lab4[i];
        if (L.x == cls) { int p = atomicAdd(&lcnt, 1); if (p < CLS_CAP) rs[p] = 4 * i; }
        if (L.y == cls) { int p = atomicAdd(&lcnt, 1); if (p < CLS_CAP) rs[p] = 4 * i + 1; }
        if (L.z == cls) { int p = atomicAdd(&lcnt, 1); if (p < CLS_CAP) rs[p] = 4 * i + 2; }
        if (L.w == cls) { int p = atomicAdd(&lcnt, 1); if (p < CLS_CAP) rs[p] = 4 * i + 3; }
    }
    __syncthreads();
    int c = min(lcnt, CLS_CAP);
    if (t == 0) cls_cnt[cls] = c;
    if (t < c) cls_rows[cls * CLS_CAP + t] = rs[t];
    int np = c * (c - 1) / 2;
    for (int base = 0; base < np * 8; base += 256) {
        int slot = base + t;
        if (slot < np * 8) {
            int p = slot >> 3, l = slot & 7;   // 8 aligned lanes per pair
            int a, b; pair_decode(p, a, b);
            const float4* pa = (const float4*)(emb + (size_t)rs[a] * D_SIZE) + l * 8;
            const float4* pb = (const float4*)(emb + (size_t)rs[b] * D_SIZE) + l * 8;
            float s = 0.0f;
#pragma unroll
            for (int k = 0; k < 8; ++k) {
                float4 x = pa[k], y = pb[k];
                s = fmaf(x.x, y.x, fmaf(x.y, y.y, fmaf(x.z, y.z, fmaf(x.w, y.w, s))));
            }
            s += __shfl_xor(s, 1, 64);
            s += __shfl_xor(s, 2, 64);
            s += __shfl_xor(s, 4, 64);
            if (l == 0) {
                if (p < PCAP) psims[cls * PCAP + p] = s;
                unsigned int e = enc_f32(s);
                atomicMin(&smin[a], e);
                atomicMin(&smin[b], e);
            }
        }
    }
    __syncthreads();
    if (t < c) pos_min[rs[t]] = dec_f32(smin[t]);
}

// ---- K2: the ONE GEMM (triangular tiles), LDS = exactly 32 KB ----
// part[k*B + row]: m-side writes k=bj (bj>=bi), n-side k=bi (bi<bj).
// C/D layout (16x16x32): col = lane&15, row = (lane>>4)*4 + reg  [m89/m91]
__global__ __launch_bounds__(256, 3) void neg_kernel(
    const unsigned short* __restrict__ embb, const int* __restrict__ labels,
    const float* __restrict__ pos_min,
    float* __restrict__ part_sum, float* __restrict__ part_max)
{
    // XCD-aware bijective swizzle (2080 % 8 == 0), then triangular decode
    int bt = (blockIdx.x & 7) * (NBLK >> 3) + (blockIdx.x >> 3);
    int bi = 0, rem = bt;
    while (rem >= (NT - bi)) { rem -= (NT - bi); ++bi; }
    const int bj = bi + rem;
    const int m0 = bi * TM, n0 = bj * TM;
    const bool isdiag = (bi == bj);

    const int tid = threadIdx.x;
    const int lane = tid & 63;
    const int w = tid >> 6;
    const int wm = w >> 1, wn = w & 1;

    __shared__ unsigned char As[2][TM * 64];
    __shared__ unsigned char Bs[2][TM * 64];

    const unsigned short* gA[2];
    const unsigned short* gB[2];
    int lofs[2];
#pragma unroll
    for (int s = 0; s < 2; ++s) {
        int r = w * 32 + s * 16 + (lane >> 2);
        int c = (lane & 3) ^ ((r >> 1) & 3);
        gA[s] = embb + (size_t)(m0 + r) * D_SIZE + c * 8;
        gB[s] = embb + (size_t)(n0 + r) * D_SIZE + c * 8;
        lofs[s] = (w * 32 + s * 16) * 64;
    }
#pragma unroll
    for (int s = 0; s < 2; ++s) { glds16(gA[s], As[0] + lofs[s]); glds16(gB[s], Bs[0] + lofs[s]); }

    const int col = lane & 15;
    const int quad = lane >> 4;
    // swizzle XOR term depends only on col -> single base per matrix,
    // f advances by a compile-time +1024 (folds into ds_read offset imm)
    const int xsw = (quad ^ ((col >> 1) & 3)) * 16;
    const int aoff0 = (wm * 64 + col) * 64 + xsw;
    const int boff0 = (wn * 64 + col) * 64 + xsw;

    f32x4 acc[4][4];
#pragma unroll
    for (int fi = 0; fi < 4; ++fi)
#pragma unroll
        for (int fj = 0; fj < 4; ++fj)
            acc[fi][fj] = (f32x4){0.0f, 0.0f, 0.0f, 0.0f};

#pragma unroll
    for (int it = 0; it < D_SIZE / TK; ++it) {
        const int st = it & 1;
        __syncthreads();   // stage st's staging complete
        if (it + 1 < D_SIZE / TK) {
            const int k1 = (it + 1) * TK;
#pragma unroll
            for (int s = 0; s < 2; ++s) {
                glds16(gA[s] + k1, As[st ^ 1] + lofs[s]);
                glds16(gB[s] + k1, Bs[st ^ 1] + lofs[s]);
            }
        }
        bf16x8 af[4], bf[4];
#pragma unroll
        for (int f = 0; f < 4; ++f) {
            af[f] = __builtin_bit_cast(bf16x8, *(const uint4*)(As[st] + aoff0 + f * 1024));
            bf[f] = __builtin_bit_cast(bf16x8, *(const uint4*)(Bs[st] + boff0 + f * 1024));
        }
#pragma unroll
        for (int fi = 0; fi < 4; ++fi)
#pragma unroll
            for (int fj = 0; fj < 4; ++fj)
                acc[fi][fj] = __builtin_amdgcn_mfma_f32_16x16x32_bf16(
                    af[fi], bf[fj], acc[fi][fj], 0, 0, 0);
    }

    // ---- branch-free sentinel epilogue, sched-fenced per fj-group ----
    // sm = diff-class ? s : -3 (sims in [-1,1]); exp2(fma(-3,K1,K2)) -> 0,
    // so masked elements add 0 to sums and -3 < any real sim for maxes.
    // Fences bound exp-temp liveness; the (256,3) budget (~168 regs) holds
    // the 64 acc + ~32 state + temps without spilling (r7/r8 spilled at 128).
    const float K1 = 72.13475204444817f;   /* BETA*log2(e) */
    const float K2 = -36.067376022224085f; /* -BETA*BASE*log2(e) */
    int ljv[4]; float pmc[4], nsn[4], nmx[4];
#pragma unroll
    for (int fj = 0; fj < 4; ++fj) {
        int cl = wn * 64 + fj * 16 + col;
        ljv[fj] = labels[n0 + cl];
        pmc[fj] = pos_min[n0 + cl] - MARGIN;
        nsn[fj] = 0.0f;
        nmx[fj] = -3.0f;
    }

#pragma unroll
    for (int fi = 0; fi < 4; ++fi) {
        int gi0 = m0 + wm * 64 + fi * 16 + quad * 4;
        int lir[4]; float pmr[4], msn[4], mmx[4];
#pragma unroll
        for (int r = 0; r < 4; ++r) {
            lir[r] = labels[gi0 + r];
            pmr[r] = pos_min[gi0 + r] - MARGIN;
            msn[r] = 0.0f;
            mmx[r] = -3.0f;
        }
        __builtin_amdgcn_sched_barrier(0);
#pragma unroll
        for (int fj = 0; fj < 4; ++fj) {
#pragma unroll
            for (int r = 0; r < 4; ++r) {
                float s = acc[fi][fj][r];
                float sm = (lir[r] != ljv[fj]) ? s : -3.0f;
                float e = fexp2(fmaf(sm, K1, K2));
                mmx[r] = fmaxf(mmx[r], sm);
                nmx[fj] = fmaxf(nmx[fj], sm);
                msn[r] += (sm > pmr[r]) ? e : 0.0f;
                nsn[fj] += (sm > pmc[fj]) ? e : 0.0f;
            }
            __builtin_amdgcn_sched_barrier(0);
        }
        // 16-lane (col) reduction via DPP — VALU, no LDS pipe
#pragma unroll
        for (int r = 0; r < 4; ++r) red16(msn[r], mmx[r]);
        if (col == 0) {
            *(float4*)(&part_sum[(size_t)bj * B_SIZE + gi0]) =
                make_float4(msn[0], msn[1], msn[2], msn[3]);
            *(float4*)(&part_max[(size_t)bj * B_SIZE + gi0]) =
                make_float4(mmx[0], mmx[1], mmx[2], mmx[3]);
        }
        __builtin_amdgcn_sched_barrier(0);
    }
    if (!isdiag) {
#pragma unroll
        for (int m = 16; m < 64; m <<= 1) {
#pragma unroll
            for (int fj = 0; fj < 4; ++fj) {
                nsn[fj] += __shfl_xor(nsn[fj], m, 64);
                nmx[fj] = fmaxf(nmx[fj], __shfl_xor(nmx[fj], m, 64));
            }
        }
        if (quad == 0) {
#pragma unroll
            for (int fj = 0; fj < 4; ++fj) {
                int gj = n0 + wn * 64 + fj * 16 + col;
                part_sum[(size_t)bi * B_SIZE + gj] = nsn[fj];
                part_max[(size_t)bi * B_SIZE + gj] = nmx[fj];
            }
        }
    }
}

// ---- K3: per-class reduce partials (8 lanes/row) + sum_pos + per-class term ----
__global__ __launch_bounds__(256) void final_kernel(
    const float* __restrict__ emb, const int* __restrict__ cls_cnt,
    const int* __restrict__ cls_rows, const float* __restrict__ psims,
    const float* __restrict__ part_sum, const float* __restrict__ part_max,
    float* __restrict__ cls_term, float* __restrict__ cls_valid) {
    int cls = blockIdx.x;
    __shared__ int rs[CLS_CAP];
    __shared__ float snm[CLS_CAP];
    __shared__ float sneg[CLS_CAP];
    __shared__ float ssum[CLS_CAP];
    int t = threadIdx.x;
    int c = min(cls_cnt[cls], CLS_CAP);
    if (t < CLS_CAP) ssum[t] = 0.0f;
    if (t < c) rs[t] = cls_rows[cls * CLS_CAP + t];
    __syncthreads();
    // reduce the 64 neg partials per row; 8 lanes per row for load parallelism
    {
        int l = t & 7;
        for (int rr = t >> 3; rr < c; rr += 32) {
            int row = rs[rr];
            float s = 0.0f, m = -__builtin_inff();
#pragma unroll
            for (int k = 0; k < 8; ++k) {
                s += part_sum[(size_t)(l * 8 + k) * B_SIZE + row];
                m = fmaxf(m, part_max[(size_t)(l * 8 + k) * B_SIZE + row]);
            }
            s += __shfl_xor(s, 1, 64); m = fmaxf(m, __shfl_xor(m, 1, 64));
            s += __shfl_xor(s, 2, 64); m = fmaxf(m, __shfl_xor(m, 2, 64));
            s += __shfl_xor(s, 4, 64); m = fmaxf(m, __shfl_xor(m, 4, 64));
            if (l == 0) { sneg[rr] = s; snm[rr] = m; }
        }
    }
    __syncthreads();
    int np = c * (c - 1) / 2;
    if (np <= PCAP) {
        for (int p = t; p < np; p += 256) {
            float s = psims[cls * PCAP + p];
            int a, b; pair_decode(p, a, b);
            float e = __expf(-ALPHA * (s - BASE));
            if (s - MARGIN < snm[a]) atomicAdd(&ssum[a], e);
            if (s - MARGIN < snm[b]) atomicAdd(&ssum[b], e);
        }
    } else {
        // fallback: recompute dots, 8 lanes per pair
        for (int base = 0; base < np * 8; base += 256) {
            int slot = base + t;
            if (slot < np * 8) {
                int p = slot >> 3, l = slot & 7;
                int a, b; pair_decode(p, a, b);
                const float4* pa = (const float4*)(emb + (size_t)rs[a] * D_SIZE) + l * 8;
                const float4* pb = (const float4*)(emb + (size_t)rs[b] * D_SIZE) + l * 8;
                float s = 0.0f;
#pragma unroll
                for (int k = 0; k < 8; ++k) {
                    float4 x = pa[k], y = pb[k];
                    s = fmaf(x.x, y.x, fmaf(x.y, y.y, fmaf(x.z, y.z, fmaf(x.w, y.w, s))));
                }
                s += __shfl_xor(s, 1, 64);
                s += __shfl_xor(s, 2, 64);
                s += __shfl_xor(s, 4, 64);
                if (l == 0) {
                    float e = __expf(-ALPHA * (s - BASE));
                    if (s - MARGIN < snm[a]) atomicAdd(&ssum[a], e);
                    if (s - MARGIN < snm[b]) atomicAdd(&ssum[b], e);
                }
            }
        }
    }
    __syncthreads();
    // per-class term: rows live on threads 0..c-1 (all in wave 0) -> shfl reduce
    if (t < 64) {
        float term = 0.0f, valid = 0.0f;
        if (t < c) {
            float sp = ssum[t], sn = sneg[t];
            if (sp > 0.0f && sn > 0.0f) {
                term = log1pf(sp) * (1.0f / ALPHA) + log1pf(sn) * (1.0f / BETA);
                valid = 1.0f;
            }
        }
#pragma unroll
        for (int m = 1; m < 64; m <<= 1) {
            term += __shfl_xor(term, m, 64);
            valid += __shfl_xor(valid, m, 64);
        }
        if (t == 0) { cls_term[cls] = term; cls_valid[cls] = valid; }
    }
}

// ---- K4: fold 1024 class terms -> out ----
__global__ __launch_bounds__(256) void finalize_kernel(
    const float* __restrict__ cls_term, const float* __restrict__ cls_valid,
    float* __restrict__ out) {
    __shared__ float st[256];
    __shared__ float sc[256];
    int t = threadIdx.x;
    float tot = 0.0f, cnt = 0.0f;
#pragma unroll
    for (int i = 0; i < N_CLS / 256; ++i) {
        tot += cls_term[i * 256 + t];
        cnt += cls_valid[i * 256 + t];
    }
    st[t] = tot; sc[t] = cnt;
    __syncthreads();
    for (int s = 128; s > 0; s >>= 1) {
        if (t < s) { st[t] += st[t + s]; sc[t] += sc[t + s]; }
        __syncthreads();
    }
    if (t == 0) out[0] = st[0] / fmaxf(sc[0], 1.0f);
}

extern "C" void kernel_launch(void* const* d_in, const int* in_sizes, int n_in,
                              void* d_out, int out_size, void* d_ws, size_t ws_size,
                              hipStream_t stream) {
    const float* emb = (const float*)d_in[0];
    const int* labels = (const int*)d_in[1];
    float* out = (float*)d_out;

    // ws: embb 4MB | part_sum 2MB | part_max 2MB | psims 1MB | cls_rows 256KB |
    //     pos_min 32KB | cls_term 4KB | cls_valid 4KB | cls_cnt 4KB
    unsigned short* embb = (unsigned short*)d_ws;
    float* part_sum = (float*)(embb + (size_t)B_SIZE * D_SIZE);
    float* part_max = part_sum + (size_t)NT * B_SIZE;
    float* psims = part_max + (size_t)NT * B_SIZE;
    int* cls_rows = (int*)(psims + (size_t)N_CLS * PCAP);
    float* pos_min = (float*)(cls_rows + N_CLS * CLS_CAP);
    float* cls_term = pos_min + B_SIZE;
    float* cls_valid = cls_term + N_CLS;
    int* cls_cnt = (int*)(cls_valid + N_CLS);

    conv_pos_kernel<<<dim3(N_CLS + NCONV), dim3(256), 0, stream>>>(
        emb, labels, embb, pos_min, psims, cls_cnt, cls_rows);
    neg_kernel<<<dim3(NBLK), dim3(256), 0, stream>>>(
        embb, labels, pos_min, part_sum, part_max);
    final_kernel<<<dim3(N_CLS), dim3(256), 0, stream>>>(
        emb, cls_cnt, cls_rows, psims, part_sum, part_max, cls_term, cls_valid);
    finalize_kernel<<<dim3(1), dim3(256), 0, stream>>>(cls_term, cls_valid, out);
}